// Round 12
// baseline (755.121 us; speedup 1.0000x reference)
//
#include <hip/hip_runtime.h>
#include <stdint.h>

typedef float f32x4 __attribute__((ext_vector_type(4)));
typedef short bf16x8 __attribute__((ext_vector_type(8)));
typedef int i32x4 __attribute__((ext_vector_type(4)));
typedef unsigned short u16;
typedef unsigned int u32;

#define MFMA16(a, b, c) __builtin_amdgcn_mfma_f32_16x16x32_bf16(a, b, c, 0, 0, 0)

__device__ __forceinline__ u16 f2b(float f) {
  union { float f; u32 u; } a; a.f = f;
  u32 r = a.u + 0x7FFF + ((a.u >> 16) & 1);
  return (u16)(r >> 16);
}
__device__ __forceinline__ float b2f(u16 b) {
  union { u32 u; float f; } a; a.u = ((u32)b) << 16;
  return a.f;
}
__device__ __forceinline__ u32 pk2(float x, float y) {
  return (u32)f2b(x) | ((u32)f2b(y) << 16);
}
__device__ __forceinline__ void glds16(const void* g, void* l) {
  __builtin_amdgcn_global_load_lds(
      (const __attribute__((address_space(1))) unsigned int*)g,
      (__attribute__((address_space(3))) unsigned int*)l, 16, 0, 0);
}
// barrier1: full per-wave drain (my glds16 + my ds_writes) then block barrier.
// After it, ALL waves' prior staging is visible (each drained its own before s_barrier).
__device__ __forceinline__ void barrier_drain() {
  asm volatile("s_waitcnt vmcnt(0) lgkmcnt(0)" ::: "memory");
  __builtin_amdgcn_sched_barrier(0);
  __builtin_amdgcn_s_barrier();
  __builtin_amdgcn_sched_barrier(0);
}
// barrier2: raw barrier, NO vm drain — in-flight glds16 (next tile's V) survives.
__device__ __forceinline__ void barrier_raw() {
  __builtin_amdgcn_sched_barrier(0);
  __builtin_amdgcn_s_barrier();
  __builtin_amdgcn_sched_barrier(0);
}

// quad-gather: lanes (m, g) hold lo (4 vals at idx 4g+j) and hi (idx 16+4g+j),
// packed as 2 dwords each. Returns 8 vals at idx 8g..8g+7 for this lane.
__device__ __forceinline__ bf16x8 quad_gather(int g, int m, u32 lo0, u32 lo1, u32 hi0, u32 hi1) {
  const int srcA = m + 16 * ((2 * g) & 3);
  const int srcB = m + 16 * ((2 * g + 1) & 3);
  const u32 Al0 = __shfl((int)lo0, srcA, 64), Al1 = __shfl((int)lo1, srcA, 64);
  const u32 Ah0 = __shfl((int)hi0, srcA, 64), Ah1 = __shfl((int)hi1, srcA, 64);
  const u32 Bl0 = __shfl((int)lo0, srcB, 64), Bl1 = __shfl((int)lo1, srcB, 64);
  const u32 Bh0 = __shfl((int)hi0, srcB, 64), Bh1 = __shfl((int)hi1, srcB, 64);
  i32x4 r;
  r.x = (int)((g < 2) ? Al0 : Ah0);
  r.y = (int)((g < 2) ? Al1 : Ah1);
  r.z = (int)((g < 2) ? Bl0 : Bh0);
  r.w = (int)((g < 2) ? Bl1 : Bh1);
  return __builtin_bit_cast(bf16x8, r);
}

__device__ __forceinline__ void conv8(const float* __restrict__ s, u16* __restrict__ d, size_t idx) {
  const float4* s4 = (const float4*)s;
  float4 a = s4[idx * 2], b = s4[idx * 2 + 1];
  i32x4 o;
  o.x = (int)pk2(a.x, a.y); o.y = (int)pk2(a.z, a.w);
  o.z = (int)pk2(b.x, b.y); o.w = (int)pk2(b.z, b.w);
  *(i32x4*)(d + idx * 8) = o;
}

// ---------------- fp32 -> bf16 convert (grid*256*8 elems exactly) ----------------
__global__ __launch_bounds__(256) void conv_f2b(const float* __restrict__ s, u16* __restrict__ d) {
  conv8(s, d, (size_t)blockIdx.x * 256 + threadIdx.x);
}

// ---------------- merged conversions: x, Wq_down, Wq_up, Wkv_up, Wkv_down(pad to 640 rows) ----------------
__global__ __launch_bounds__(256) void conv_all(
    const float* __restrict__ x, const float* __restrict__ wqd_s, const float* __restrict__ wqu_s,
    const float* __restrict__ wkvu_s, const float* __restrict__ wkvd_s,
    u16* __restrict__ x_d, u16* __restrict__ wqd_d, u16* __restrict__ wqu_d,
    u16* __restrict__ wkvu_d, u16* __restrict__ wkvd_d) {
  int bb = blockIdx.x;
  if (bb < 4096) { conv8(x, x_d, (size_t)bb * 256 + threadIdx.x); return; }
  bb -= 4096;
  if (bb < 1024) { conv8(wqd_s, wqd_d, (size_t)bb * 256 + threadIdx.x); return; }
  bb -= 1024;
  if (bb < 1536) { conv8(wqu_s, wqu_d, (size_t)bb * 256 + threadIdx.x); return; }
  bb -= 1536;
  if (bb < 1024) { conv8(wkvu_s, wkvu_d, (size_t)bb * 256 + threadIdx.x); return; }
  bb -= 1024;
  {  // Wkv_down (576,2048) -> (640,2048) zero-padded
    const size_t idx = (size_t)bb * 256 + threadIdx.x;
    const size_t e0 = idx * 8;
    const int row = (int)(e0 >> 11);
    i32x4 o;
    if (row < 576) {
      const float4* s4 = (const float4*)wkvd_s;
      float4 a = s4[idx * 2], b = s4[idx * 2 + 1];
      o.x = (int)pk2(a.x, a.y); o.y = (int)pk2(a.z, a.w);
      o.z = (int)pk2(b.x, b.y); o.w = (int)pk2(b.z, b.w);
    } else {
      o.x = 0; o.y = 0; o.z = 0; o.w = 0;
    }
    *(i32x4*)(wkvd_d + e0) = o;
  }
}

// ---------------- wupt[h][k][d] (bf16) = Wkv_up[h*256+d][k], d in [0,128) ----------------
__global__ __launch_bounds__(256) void transpose_wup(const float* __restrict__ s, u16* __restrict__ d) {
  __shared__ float tile[32][33];
  const int tx = threadIdx.x & 31, ty = threadIdx.x >> 5;
  const int h = blockIdx.z, nt = blockIdx.x, dt = blockIdx.y;
#pragma unroll
  for (int i = 0; i < 4; ++i)
    tile[ty + i * 8][tx] = s[(size_t)(h * 256 + dt * 32 + ty + i * 8) * 512 + nt * 32 + tx];
  __syncthreads();
#pragma unroll
  for (int i = 0; i < 4; ++i)
    d[(size_t)(h * 512 + nt * 32 + ty + i * 8) * 128 + dt * 32 + tx] = f2b(tile[tx][ty + i * 8]);
}

// ---------------- kvT[b][c][t] (bf16) = kvc[b*1024+t][c], c in [0,512) ----------------
__global__ __launch_bounds__(256) void transpose_kvT(const u16* __restrict__ s, u16* __restrict__ d) {
  __shared__ u16 tile[32][33];
  const int tx = threadIdx.x & 31, ty = threadIdx.x >> 5;
  const int b = blockIdx.z, tt = blockIdx.x, ct = blockIdx.y;
#pragma unroll
  for (int i = 0; i < 4; ++i)
    tile[ty + i * 8][tx] = s[(size_t)(b * 1024 + tt * 32 + ty + i * 8) * 576 + ct * 32 + tx];
  __syncthreads();
#pragma unroll
  for (int i = 0; i < 4; ++i)
    d[(size_t)(b * 512 + ct * 32 + ty + i * 8) * 1024 + tt * 32 + tx] = tile[tx][ty + i * 8];
}

// ---------------- RMSNorm rows of 1024: f32 in -> bf16 out ----------------
__global__ __launch_bounds__(64) void rmsnorm1024_b(const float* __restrict__ t, const float* __restrict__ w,
                                                    u16* __restrict__ o) {
  const int row = blockIdx.x, lane = threadIdx.x;
  const float4* p = (const float4*)(t + (size_t)row * 1024);
  const float4* w4 = (const float4*)w;
  float4 v[4];
  float ss = 0.f;
#pragma unroll
  for (int i = 0; i < 4; ++i) {
    v[i] = p[lane * 4 + i];
    ss += v[i].x * v[i].x + v[i].y * v[i].y + v[i].z * v[i].z + v[i].w * v[i].w;
  }
#pragma unroll
  for (int off = 32; off >= 1; off >>= 1) ss += __shfl_xor(ss, off, 64);
  const float rms = rsqrtf(ss * (1.0f / 1024.0f) + 1e-6f);
  u16* ob = o + (size_t)row * 1024 + lane * 16;
#pragma unroll
  for (int i2 = 0; i2 < 2; ++i2) {
    float4 a = v[i2 * 2], wa = w4[lane * 4 + i2 * 2];
    float4 b = v[i2 * 2 + 1], wb = w4[lane * 4 + i2 * 2 + 1];
    i32x4 pk;
    pk.x = (int)pk2(a.x * rms * wa.x, a.y * rms * wa.y);
    pk.y = (int)pk2(a.z * rms * wa.z, a.w * rms * wa.w);
    pk.z = (int)pk2(b.x * rms * wb.x, b.y * rms * wb.y);
    pk.w = (int)pk2(b.z * rms * wb.z, b.w * rms * wb.w);
    *(i32x4*)(ob + i2 * 8) = pk;
  }
}

// ---------------- kvp (4096,640 f32) -> kvc (4096,576 bf16): rmsnorm 512 + rope 64 ----------------
__global__ __launch_bounds__(64) void prep_kv(const float* __restrict__ kv, const float* __restrict__ freq,
                                              const float* __restrict__ w, u16* __restrict__ kvc) {
  const int row = blockIdx.x, lane = threadIdx.x;
  const int l = row & 1023;
  const float* src = kv + (size_t)row * 640;
  const float4* s4 = (const float4*)src;
  const float4* w4 = (const float4*)w;
  float4 v[2];
  float ss = 0.f;
#pragma unroll
  for (int i = 0; i < 2; ++i) {
    v[i] = s4[lane * 2 + i];
    ss += v[i].x * v[i].x + v[i].y * v[i].y + v[i].z * v[i].z + v[i].w * v[i].w;
  }
#pragma unroll
  for (int off = 32; off >= 1; off >>= 1) ss += __shfl_xor(ss, off, 64);
  const float rms = rsqrtf(ss * (1.0f / 512.0f) + 1e-6f);
  u16* dst = kvc + (size_t)row * 576;
  {
    float4 a = v[0], wa = w4[lane * 2];
    float4 b = v[1], wb = w4[lane * 2 + 1];
    i32x4 pk;
    pk.x = (int)pk2(a.x * rms * wa.x, a.y * rms * wa.y);
    pk.y = (int)pk2(a.z * rms * wa.z, a.w * rms * wa.w);
    pk.z = (int)pk2(b.x * rms * wb.x, b.y * rms * wb.y);
    pk.w = (int)pk2(b.z * rms * wb.z, b.w * rms * wb.w);
    *(i32x4*)(dst + lane * 8) = pk;
  }
  if (lane < 32) {
    const int j = lane;
    const float re = src[512 + 2 * j], im = src[512 + 2 * j + 1];
    const float c = freq[(l * 32 + j) * 2], s = freq[(l * 32 + j) * 2 + 1];
    dst[512 + 2 * j] = f2b(re * c - im * s);
    dst[512 + 2 * j + 1] = f2b(re * s + im * c);
  }
}

// ---------------- rope on q_bf[row][h*192+128..192] -> qcat[h][row][512..576] ----------------
__global__ __launch_bounds__(256) void rope_pack_q(const u16* __restrict__ q, const float* __restrict__ freq,
                                                   u16* __restrict__ qcat) {
  const int row = blockIdx.x;
  const int l = row & 1023;
  const int h = threadIdx.x >> 4, t = threadIdx.x & 15;
  const u16* qs = q + (size_t)row * 3072 + h * 192 + 128;
  u16* qd = qcat + ((size_t)h * 4096 + row) * 576 + 512;
  const float* fr = freq + (size_t)l * 64;
#pragma unroll
  for (int i = 0; i < 2; ++i) {
    const int j = 2 * t + i;
    const float re = b2f(qs[2 * j]), im = b2f(qs[2 * j + 1]);
    const float c = fr[2 * j], s = fr[2 * j + 1];
    qd[2 * j] = f2b(re * c - im * s);
    qd[2 * j + 1] = f2b(re * s + im * c);
  }
}

// ---------------- bf16 NT GEMM (m97-style): 128x128 tile, BK=64, global_load_lds w16 ----------------
// Optional z-batch via element strides sA/sB/sC.
template <typename OUT>
__global__ __launch_bounds__(256) void gemm_nt_bf16(const u16* __restrict__ A, const u16* __restrict__ B,
                                                    OUT* __restrict__ C, int K, int lda, int ldb, int ldc,
                                                    long sA, long sB, long sC) {
  __shared__ u16 lA[128 * 64];
  __shared__ u16 lB[128 * 64];
  const int tid = threadIdx.x, lane = tid & 63, w = tid >> 6;
  const int m = lane & 15, g = lane >> 4;
  const int wm = (w & 1) * 64, wn = (w >> 1) * 64;
  const int m0 = blockIdx.y * 128, n0 = blockIdx.x * 128;
  A += (long)blockIdx.z * sA;
  B += (long)blockIdx.z * sB;
  C += (long)blockIdx.z * sC;
  const int lrow = lane >> 3, lcol = (lane & 7) * 8;
  f32x4 acc[4][4];
#pragma unroll
  for (int i = 0; i < 4; ++i)
#pragma unroll
    for (int j = 0; j < 4; ++j) acc[i][j] = (f32x4)(0.0f);

  for (int k0 = 0; k0 < K; k0 += 64) {
    __syncthreads();
#pragma unroll
    for (int c = 0; c < 4; ++c) {
      const int ch = w * 4 + c;
      glds16(A + (size_t)(m0 + ch * 8 + lrow) * lda + k0 + lcol, &lA[ch * 512]);
      glds16(B + (size_t)(n0 + ch * 8 + lrow) * ldb + k0 + lcol, &lB[ch * 512]);
    }
    __syncthreads();
#pragma unroll
    for (int ks = 0; ks < 2; ++ks) {
      bf16x8 af[4], bfr[4];
#pragma unroll
      for (int i = 0; i < 4; ++i) {
        af[i] = *(const bf16x8*)&lA[(wm + i * 16 + m) * 64 + ks * 32 + g * 8];
        bfr[i] = *(const bf16x8*)&lB[(wn + i * 16 + m) * 64 + ks * 32 + g * 8];
      }
#pragma unroll
      for (int i = 0; i < 4; ++i)
#pragma unroll
        for (int j = 0; j < 4; ++j) acc[i][j] = MFMA16(af[i], bfr[j], acc[i][j]);
    }
  }
  // C/D layout: col = lane&15, row = (lane>>4)*4 + reg
#pragma unroll
  for (int i = 0; i < 4; ++i)
#pragma unroll
    for (int j = 0; j < 4; ++j)
#pragma unroll
      for (int jj = 0; jj < 4; ++jj) {
        const size_t off = (size_t)(m0 + wm + i * 16 + g * 4 + jj) * ldc + n0 + wn + j * 16 + m;
        if constexpr (sizeof(OUT) == 2) C[off] = f2b(acc[i][j][jj]);
        else C[off] = acc[i][j][jj];
      }
}

// ---------------- fused MLA attention, 8 heads per block (KV staged once) ----------------
// grid 256 blocks (1/CU), 512 thr = 8 waves; wave w owns head hg*8+w.
// latent_out written in-place into qcat[h][row][0:512].
// VT double-buffered: glds16 for tile t+1 issued after barrier1(t), drained at
// barrier1(t+1) (per-wave vmcnt(0) + s_barrier => cross-wave visible). barrier2 = raw.
__global__ __launch_bounds__(512, 2) void mla_attn(
    u16* __restrict__ qcat,         // (16, 4096, 576): in = [q_abs|q_rope], out[0:512] = latent
    const u16* __restrict__ kvc,    // (4096, 576)
    const u16* __restrict__ kvT) {  // (4, 512, 1024) latent transposed
  __shared__ u16 SM[80640];  // [0,19200) KL | [19200,35584) VT0 | [35584,51968) VT1 | [51968,80640) QL
  u16* KL = SM;
  u16* VT0 = SM + 19200;
  u16* VT1 = SM + 35584;
  u16* QLb = SM + 51968;          // 8 waves x 7 frags x 512 u16
  const int tid = threadIdx.x, lane = tid & 63, w = tid >> 6;   // w = 0..7
  const int m = lane & 15, g = lane >> 4;
  // swizzle: f and f+8 share (qp, b) and land on the same XCD (id % 8)
  const int f = (int)blockIdx.x;
  const int group = (f & 7) * 16 + (f >> 4);   // 0..127
  const int hg = (f >> 3) & 1;
  const int qp = group & 31;
  const int b = group >> 5;
  const int h = hg * 8 + w;
  const float scale = 0.07216878364870323f; // 1/sqrt(192)
  const u16* kvb = kvc + (size_t)b * 1024 * 576;
  const u16* kvTb = kvT + (size_t)b * 512 * 1024;
  u16* qlw = &QLb[w * 3584];                 // this wave's Q-LDS (7 x 512 u16)
  const int sg8 = (g ^ ((m >> 1) & 3)) * 8;  // bank-spread slot for VT/QL
  const int vls = ((lane & 3) ^ ((lane >> 3) & 3)) * 8;  // pre-swizzled V global sub-offset

#pragma unroll 1
  for (int ps = 0; ps < 2; ++ps) {
    const int qt = ps ? (63 - qp) : qp;
    const int l0 = qt * 16;
    const int row = l0 + m;                  // q position of lane's column
    const int nt = (qt >> 1) + 1;            // tiles with t0 <= l0+15

    // prologue: qh[0..10] in regs; qh[11..17] -> wave-private LDS (swizzled slot)
    bf16x8 qh[11];
    {
      const u16* qb = qcat + ((size_t)h * 4096 + b * 1024 + row) * 576 + g * 8;
#pragma unroll
      for (int ks = 0; ks < 11; ++ks) qh[ks] = *(const bf16x8*)(qb + ks * 32);
#pragma unroll
      for (int kk = 0; kk < 7; ++kk) {
        bf16x8 v = *(const bf16x8*)(qb + (11 + kk) * 32);
        *(bf16x8*)&qlw[kk * 512 + m * 32 + sg8] = v;
      }
    }

    f32x4 o[32];
#pragma unroll
    for (int i = 0; i < 32; ++i) o[i] = (f32x4)(0.0f);
    float mrow = -INFINITY, ssum = 0.f;

    // issue V(0) -> VT0 (drained at barrier1 of tile 0)
#pragma unroll
    for (int c = 0; c < 4; ++c) {
      const int cc = w * 4 + c;
      glds16(kvTb + (size_t)(cc * 16 + (lane >> 2)) * 1024 + vls, &VT0[cc * 512]);
    }

#pragma unroll 1
    for (int it = 0; it < nt; ++it) {
      const int t0 = it * 32;
      u16* VTc = (it & 1) ? VT1 : VT0;
      u16* VTn = (it & 1) ? VT0 : VT1;
      // stage K(t): direct reg staging (KL safe: all waves past barrier2(t-1))
#pragma unroll
      for (int k = 0; k < 4; ++k) {
        const int s = tid + k * 512, t = s / 72, c8 = (s % 72) * 8;
        *(bf16x8*)&KL[t * 600 + c8] = *(const bf16x8*)(kvb + (size_t)(t0 + t) * 576 + c8);
      }
      if (tid < 256) {
        const int s = 2048 + tid, t = s / 72, c8 = (s % 72) * 8;
        *(bf16x8*)&KL[t * 600 + c8] = *(const bf16x8*)(kvb + (size_t)(t0 + t) * 576 + c8);
      }
      barrier_drain();   // V(t) + K(t) visible to all waves
      // issue V(t+1) -> VTn; flies across this tile's compute, drained at next barrier_drain
      if (it + 1 < nt) {
#pragma unroll
        for (int c = 0; c < 4; ++c) {
          const int cc = w * 4 + c;
          glds16(kvTb + (size_t)(cc * 16 + (lane >> 2)) * 1024 + (t0 + 32) + vls, &VTn[cc * 512]);
        }
      }
      // QK^T (swapped): A = K rows, B = q-frags (regs ks<11, LDS ks>=11)
      f32x4 st0 = (f32x4)(0.0f), st1 = (f32x4)(0.0f);
      __builtin_amdgcn_s_setprio(1);
#pragma unroll
      for (int ks = 0; ks < 11; ++ks) {
        bf16x8 a0 = *(const bf16x8*)&KL[m * 600 + ks * 32 + g * 8];
        bf16x8 a1 = *(const bf16x8*)&KL[(m + 16) * 600 + ks * 32 + g * 8];
        st0 = MFMA16(a0, qh[ks], st0);
        st1 = MFMA16(a1, qh[ks], st1);
      }
#pragma unroll
      for (int ks = 11; ks < 18; ++ks) {
        bf16x8 a0 = *(const bf16x8*)&KL[m * 600 + ks * 32 + g * 8];
        bf16x8 a1 = *(const bf16x8*)&KL[(m + 16) * 600 + ks * 32 + g * 8];
        const bf16x8 bq = *(const bf16x8*)&qlw[(ks - 11) * 512 + m * 32 + sg8];
        st0 = MFMA16(a0, bq, st0);
        st1 = MFMA16(a1, bq, st1);
      }
      __builtin_amdgcn_s_setprio(0);
      float p[8];
      float mt = -INFINITY;
#pragma unroll
      for (int j = 0; j < 4; ++j) {
        const int ta = t0 + 4 * g + j;
        const float sa = (ta <= row) ? st0[j] * scale : -INFINITY;
        const float sb = (ta + 16 <= row) ? st1[j] * scale : -INFINITY;
        p[j] = sa; p[4 + j] = sb;
        mt = fmaxf(mt, fmaxf(sa, sb));
      }
      mt = fmaxf(mt, __shfl_xor(mt, 16, 64));
      mt = fmaxf(mt, __shfl_xor(mt, 32, 64));
      // T13 defer-max: only rescale when the row max actually grows
      if (__any(mt > mrow + 8.0f)) {
        const float mnew = fmaxf(mrow, mt);
        const float corr = __expf(mrow - mnew);
        float cj[4];
#pragma unroll
        for (int j = 0; j < 4; ++j) cj[j] = __shfl(corr, 4 * g + j, 64);
#pragma unroll
        for (int i = 0; i < 32; ++i) {
          o[i][0] *= cj[0]; o[i][1] *= cj[1]; o[i][2] *= cj[2]; o[i][3] *= cj[3];
        }
        ssum *= corr;
        mrow = mnew;
      }
      float psum = 0.f;
#pragma unroll
      for (int i = 0; i < 8; ++i) { p[i] = __expf(p[i] - mrow); psum += p[i]; }
      psum += __shfl_xor(psum, 16, 64);
      psum += __shfl_xor(psum, 32, 64);
      ssum += psum;
      const bf16x8 pa = quad_gather(g, m, pk2(p[0], p[1]), pk2(p[2], p[3]),
                                          pk2(p[4], p[5]), pk2(p[6], p[7]));
      __builtin_amdgcn_s_setprio(1);
#pragma unroll
      for (int nf = 0; nf < 32; ++nf) {
        const bf16x8 bfr = *(const bf16x8*)&VTc[(nf * 16 + m) * 32 + sg8];
        o[nf] = MFMA16(pa, bfr, o[nf]);
      }
      __builtin_amdgcn_s_setprio(0);
      barrier_raw();   // all compute done; in-flight V(t+1) glds16 survives
    }

    // normalize
    {
      const float inv = 1.f / ssum;
      float ij[4];
#pragma unroll
      for (int j = 0; j < 4; ++j) ij[j] = __shfl(inv, 4 * g + j, 64);
#pragma unroll
      for (int i = 0; i < 32; ++i) {
        o[i][0] *= ij[0]; o[i][1] *= ij[1]; o[i][2] *= ij[2]; o[i][3] *= ij[3];
      }
    }
    // write latent_out in-place into qcat[h][b*1024+l0 .. +15][0:512]
    // Ob overlays KL+VT0 (67.6KB < 71.2KB): safe, all compute done at last barrier_raw.
    u16* Ob = &SM[w * 4224];                 // per-wave 16 x 264
#pragma unroll
    for (int hh = 0; hh < 2; ++hh) {
#pragma unroll
      for (int i = 0; i < 16; ++i)
#pragma unroll
        for (int j = 0; j < 4; ++j)
          Ob[(4 * g + j) * 264 + i * 16 + m] = f2b(o[hh * 16 + i][j]);
      u16* lat = qcat + ((size_t)h * 4096 + b * 1024 + l0) * 576 + hh * 256;
#pragma unroll
      for (int k = 0; k < 8; ++k) {
        const int cc = lane + k * 64;        // 0..511: 16 rows x 32 chunks of 8
        const int r = cc >> 5, c8 = (cc & 31) * 8;
        *(bf16x8*)(lat + (size_t)r * 576 + c8) = *(const bf16x8*)&Ob[r * 264 + c8];
      }
    }
    __syncthreads();   // full drain: next ps restages KL/VT0 over Ob region
  }
}

extern "C" void kernel_launch(void* const* d_in, const int* in_sizes, int n_in,
                              void* d_out, int out_size, void* d_ws, size_t ws_size,
                              hipStream_t stream) {
  const float* x        = (const float*)d_in[0];
  const float* freq     = (const float*)d_in[2];
  const float* Wq_down  = (const float*)d_in[4];
  const float* Wq_up    = (const float*)d_in[5];
  const float* Wkv_down = (const float*)d_in[6];
  const float* Wkv_up   = (const float*)d_in[7];
  const float* Wout     = (const float*)d_in[8];
  const float* rms_q_w  = (const float*)d_in[9];
  const float* rms_kv_w = (const float*)d_in[10];
  float* out = (float*)d_out;

  // Phase-overlapped arena, total 115.9 MB (< proven 120.6 MB budget).
  char* B = (char*)d_ws;                           // 75,497,472 B
  char* A = B + (size_t)75497472;                  // 25,165,824 B
  char* C = A + (size_t)25165824;                  // 15,204,352 B
  // B region, phases 1-3 (all dead before qcat is written):
  u16*   x_bf = (u16*)(B);                         // 16,777,216
  float* t0   = (float*)(B + 16777216);            // 16,777,216
  u16*   t0b  = (u16*)(B + 33554432);              //  8,388,608
  u16*   wqd  = (u16*)(B + 41943040);              //  4,194,304
  u16*   wqu  = (u16*)(B + 46137344);              //  6,291,456
  u16*   wkvd = (u16*)(B + 52428800);              //  2,621,440
  float* kvp  = (float*)(B + 55050240);            // 10,485,760 (ends 65,536,000)
  // B region, phase 4-6: qcat (becomes latent in-place)
  u16*   qcat  = (u16*)(B);                        // 75,497,472
  // A region: q_bf (phases 2-4), then vout + woutb (phase 6-7)
  u16*   q_bf = (u16*)(A);                         // 25,165,824
  u16*   vout = (u16*)(A);                         // 16,777,216
  u16*   woutb = (u16*)(A + 16777216);             //  8,388,608 (after q_bf dead)
  // C region: persistent small buffers
  u16*   kvc  = (u16*)(C);                         //  4,718,592
  u16*   kvT  = (u16*)(C + 4718592);               //  4,194,304
  u16*   wupt = (u16*)(C + 8912896);               //  2,097,152
  u16*   wkvu = (u16*)(C + 11010048);              //  4,194,304

  // conversions (merged) + weight transpose
  conv_all<<<8320, 256, 0, stream>>>(x, Wq_down, Wq_up, Wkv_up, Wkv_down,
                                     x_bf, wqd, wqu, wkvu, wkvd);
  transpose_wup<<<dim3(16, 4, 16), 256, 0, stream>>>(Wkv_up, wupt);
  // q path
  gemm_nt_bf16<float><<<dim3(8, 32), 256, 0, stream>>>(x_bf, wqd, t0, 2048, 2048, 2048, 1024, 0, 0, 0);
  rmsnorm1024_b<<<4096, 64, 0, stream>>>(t0, rms_q_w, t0b);
  gemm_nt_bf16<u16><<<dim3(24, 32), 256, 0, stream>>>(t0b, wqu, q_bf, 1024, 1024, 1024, 3072, 0, 0, 0);
  // kv path
  gemm_nt_bf16<float><<<dim3(5, 32), 256, 0, stream>>>(x_bf, wkvd, kvp, 2048, 2048, 2048, 640, 0, 0, 0);
  prep_kv<<<4096, 64, 0, stream>>>(kvp, freq, rms_kv_w, kvc);
  transpose_kvT<<<dim3(32, 16, 4), 256, 0, stream>>>(kvc, kvT);
  // qcat = [q_abs | rope(q_rope)]  (overwrites B phase-1 buffers; they are dead)
  rope_pack_q<<<4096, 256, 0, stream>>>(q_bf, freq, qcat);
  gemm_nt_bf16<u16><<<dim3(4, 32, 16), 256, 0, stream>>>(q_bf, wupt, qcat, 128, 3072, 128, 576,
                                                         192, (long)512 * 128, (long)4096 * 576);
  // fused attention: qcat[...][0:512] becomes latent_out in-place (q_bf dead)
  mla_attn<<<dim3(256), 512, 0, stream>>>(qcat, kvc, kvT);
  // v_out = latent @ Wv^T per head (batched): vout[row][h*128+d]
  gemm_nt_bf16<u16><<<dim3(1, 32, 16), 256, 0, stream>>>(
      qcat, wkvu + (size_t)128 * 512, vout, 512, 576, 512, 2048,
      (long)4096 * 576, (long)256 * 512, 128);
  // final projection (woutb into dead upper-A region)
  conv_f2b<<<2048, 256, 0, stream>>>(Wout, woutb);
  gemm_nt_bf16<float><<<dim3(16, 32), 256, 0, stream>>>(vout, woutb, out, 2048, 2048, 2048, 2048, 0, 0, 0);
}

// Round 13
// 402.380 us; speedup vs baseline: 1.8766x; 1.8766x over previous
//
#include <hip/hip_runtime.h>
#include <stdint.h>

typedef float f32x4 __attribute__((ext_vector_type(4)));
typedef short bf16x8 __attribute__((ext_vector_type(8)));
typedef int i32x4 __attribute__((ext_vector_type(4)));
typedef unsigned short u16;
typedef unsigned int u32;

#define MFMA16(a, b, c) __builtin_amdgcn_mfma_f32_16x16x32_bf16(a, b, c, 0, 0, 0)

__device__ __forceinline__ u16 f2b(float f) {
  union { float f; u32 u; } a; a.f = f;
  u32 r = a.u + 0x7FFF + ((a.u >> 16) & 1);
  return (u16)(r >> 16);
}
__device__ __forceinline__ float b2f(u16 b) {
  union { u32 u; float f; } a; a.u = ((u32)b) << 16;
  return a.f;
}
__device__ __forceinline__ u32 pk2(float x, float y) {
  return (u32)f2b(x) | ((u32)f2b(y) << 16);
}
__device__ __forceinline__ void glds16(const void* g, void* l) {
  __builtin_amdgcn_global_load_lds(
      (const __attribute__((address_space(1))) unsigned int*)g,
      (__attribute__((address_space(3))) unsigned int*)l, 16, 0, 0);
}

// quad-gather: lanes (m, g) hold lo (4 vals at idx 4g+j) and hi (idx 16+4g+j),
// packed as 2 dwords each. Returns 8 vals at idx 8g..8g+7 for this lane.
__device__ __forceinline__ bf16x8 quad_gather(int g, int m, u32 lo0, u32 lo1, u32 hi0, u32 hi1) {
  const int srcA = m + 16 * ((2 * g) & 3);
  const int srcB = m + 16 * ((2 * g + 1) & 3);
  const u32 Al0 = __shfl((int)lo0, srcA, 64), Al1 = __shfl((int)lo1, srcA, 64);
  const u32 Ah0 = __shfl((int)hi0, srcA, 64), Ah1 = __shfl((int)hi1, srcA, 64);
  const u32 Bl0 = __shfl((int)lo0, srcB, 64), Bl1 = __shfl((int)lo1, srcB, 64);
  const u32 Bh0 = __shfl((int)hi0, srcB, 64), Bh1 = __shfl((int)hi1, srcB, 64);
  i32x4 r;
  r.x = (int)((g < 2) ? Al0 : Ah0);
  r.y = (int)((g < 2) ? Al1 : Ah1);
  r.z = (int)((g < 2) ? Bl0 : Bh0);
  r.w = (int)((g < 2) ? Bl1 : Bh1);
  return __builtin_bit_cast(bf16x8, r);
}

__device__ __forceinline__ void conv8(const float* __restrict__ s, u16* __restrict__ d, size_t idx) {
  const float4* s4 = (const float4*)s;
  float4 a = s4[idx * 2], b = s4[idx * 2 + 1];
  i32x4 o;
  o.x = (int)pk2(a.x, a.y); o.y = (int)pk2(a.z, a.w);
  o.z = (int)pk2(b.x, b.y); o.w = (int)pk2(b.z, b.w);
  *(i32x4*)(d + idx * 8) = o;
}

// ---------------- fp32 -> bf16 convert (grid*256*8 elems exactly) ----------------
__global__ __launch_bounds__(256) void conv_f2b(const float* __restrict__ s, u16* __restrict__ d) {
  conv8(s, d, (size_t)blockIdx.x * 256 + threadIdx.x);
}

// ---------------- merged conversions: x, Wq_down, Wq_up, Wkv_up, Wkv_down(pad to 640 rows) ----------------
__global__ __launch_bounds__(256) void conv_all(
    const float* __restrict__ x, const float* __restrict__ wqd_s, const float* __restrict__ wqu_s,
    const float* __restrict__ wkvu_s, const float* __restrict__ wkvd_s,
    u16* __restrict__ x_d, u16* __restrict__ wqd_d, u16* __restrict__ wqu_d,
    u16* __restrict__ wkvu_d, u16* __restrict__ wkvd_d) {
  int bb = blockIdx.x;
  if (bb < 4096) { conv8(x, x_d, (size_t)bb * 256 + threadIdx.x); return; }
  bb -= 4096;
  if (bb < 1024) { conv8(wqd_s, wqd_d, (size_t)bb * 256 + threadIdx.x); return; }
  bb -= 1024;
  if (bb < 1536) { conv8(wqu_s, wqu_d, (size_t)bb * 256 + threadIdx.x); return; }
  bb -= 1536;
  if (bb < 1024) { conv8(wkvu_s, wkvu_d, (size_t)bb * 256 + threadIdx.x); return; }
  bb -= 1024;
  {  // Wkv_down (576,2048) -> (640,2048) zero-padded
    const size_t idx = (size_t)bb * 256 + threadIdx.x;
    const size_t e0 = idx * 8;
    const int row = (int)(e0 >> 11);
    i32x4 o;
    if (row < 576) {
      const float4* s4 = (const float4*)wkvd_s;
      float4 a = s4[idx * 2], b = s4[idx * 2 + 1];
      o.x = (int)pk2(a.x, a.y); o.y = (int)pk2(a.z, a.w);
      o.z = (int)pk2(b.x, b.y); o.w = (int)pk2(b.z, b.w);
    } else {
      o.x = 0; o.y = 0; o.z = 0; o.w = 0;
    }
    *(i32x4*)(wkvd_d + e0) = o;
  }
}

// ---------------- wupt[h][k][d] (bf16) = Wkv_up[h*256+d][k], d in [0,128) ----------------
__global__ __launch_bounds__(256) void transpose_wup(const float* __restrict__ s, u16* __restrict__ d) {
  __shared__ float tile[32][33];
  const int tx = threadIdx.x & 31, ty = threadIdx.x >> 5;
  const int h = blockIdx.z, nt = blockIdx.x, dt = blockIdx.y;
#pragma unroll
  for (int i = 0; i < 4; ++i)
    tile[ty + i * 8][tx] = s[(size_t)(h * 256 + dt * 32 + ty + i * 8) * 512 + nt * 32 + tx];
  __syncthreads();
#pragma unroll
  for (int i = 0; i < 4; ++i)
    d[(size_t)(h * 512 + nt * 32 + ty + i * 8) * 128 + dt * 32 + tx] = f2b(tile[tx][ty + i * 8]);
}

// ---------------- kvT[b][c][t] (bf16) = kvc[b*1024+t][c], c in [0,512) ----------------
__global__ __launch_bounds__(256) void transpose_kvT(const u16* __restrict__ s, u16* __restrict__ d) {
  __shared__ u16 tile[32][33];
  const int tx = threadIdx.x & 31, ty = threadIdx.x >> 5;
  const int b = blockIdx.z, tt = blockIdx.x, ct = blockIdx.y;
#pragma unroll
  for (int i = 0; i < 4; ++i)
    tile[ty + i * 8][tx] = s[(size_t)(b * 1024 + tt * 32 + ty + i * 8) * 576 + ct * 32 + tx];
  __syncthreads();
#pragma unroll
  for (int i = 0; i < 4; ++i)
    d[(size_t)(b * 512 + ct * 32 + ty + i * 8) * 1024 + tt * 32 + tx] = tile[tx][ty + i * 8];
}

// ---------------- RMSNorm rows of 1024: f32 in -> bf16 out ----------------
__global__ __launch_bounds__(64) void rmsnorm1024_b(const float* __restrict__ t, const float* __restrict__ w,
                                                    u16* __restrict__ o) {
  const int row = blockIdx.x, lane = threadIdx.x;
  const float4* p = (const float4*)(t + (size_t)row * 1024);
  const float4* w4 = (const float4*)w;
  float4 v[4];
  float ss = 0.f;
#pragma unroll
  for (int i = 0; i < 4; ++i) {
    v[i] = p[lane * 4 + i];
    ss += v[i].x * v[i].x + v[i].y * v[i].y + v[i].z * v[i].z + v[i].w * v[i].w;
  }
#pragma unroll
  for (int off = 32; off >= 1; off >>= 1) ss += __shfl_xor(ss, off, 64);
  const float rms = rsqrtf(ss * (1.0f / 1024.0f) + 1e-6f);
  u16* ob = o + (size_t)row * 1024 + lane * 16;
#pragma unroll
  for (int i2 = 0; i2 < 2; ++i2) {
    float4 a = v[i2 * 2], wa = w4[lane * 4 + i2 * 2];
    float4 b = v[i2 * 2 + 1], wb = w4[lane * 4 + i2 * 2 + 1];
    i32x4 pk;
    pk.x = (int)pk2(a.x * rms * wa.x, a.y * rms * wa.y);
    pk.y = (int)pk2(a.z * rms * wa.z, a.w * rms * wa.w);
    pk.z = (int)pk2(b.x * rms * wb.x, b.y * rms * wb.y);
    pk.w = (int)pk2(b.z * rms * wb.z, b.w * rms * wb.w);
    *(i32x4*)(ob + i2 * 8) = pk;
  }
}

// ---------------- kvp (4096,640 f32) -> kvc (4096,576 bf16): rmsnorm 512 + rope 64 ----------------
__global__ __launch_bounds__(64) void prep_kv(const float* __restrict__ kv, const float* __restrict__ freq,
                                              const float* __restrict__ w, u16* __restrict__ kvc) {
  const int row = blockIdx.x, lane = threadIdx.x;
  const int l = row & 1023;
  const float* src = kv + (size_t)row * 640;
  const float4* s4 = (const float4*)src;
  const float4* w4 = (const float4*)w;
  float4 v[2];
  float ss = 0.f;
#pragma unroll
  for (int i = 0; i < 2; ++i) {
    v[i] = s4[lane * 2 + i];
    ss += v[i].x * v[i].x + v[i].y * v[i].y + v[i].z * v[i].z + v[i].w * v[i].w;
  }
#pragma unroll
  for (int off = 32; off >= 1; off >>= 1) ss += __shfl_xor(ss, off, 64);
  const float rms = rsqrtf(ss * (1.0f / 512.0f) + 1e-6f);
  u16* dst = kvc + (size_t)row * 576;
  {
    float4 a = v[0], wa = w4[lane * 2];
    float4 b = v[1], wb = w4[lane * 2 + 1];
    i32x4 pk;
    pk.x = (int)pk2(a.x * rms * wa.x, a.y * rms * wa.y);
    pk.y = (int)pk2(a.z * rms * wa.z, a.w * rms * wa.w);
    pk.z = (int)pk2(b.x * rms * wb.x, b.y * rms * wb.y);
    pk.w = (int)pk2(b.z * rms * wb.z, b.w * rms * wb.w);
    *(i32x4*)(dst + lane * 8) = pk;
  }
  if (lane < 32) {
    const int j = lane;
    const float re = src[512 + 2 * j], im = src[512 + 2 * j + 1];
    const float c = freq[(l * 32 + j) * 2], s = freq[(l * 32 + j) * 2 + 1];
    dst[512 + 2 * j] = f2b(re * c - im * s);
    dst[512 + 2 * j + 1] = f2b(re * s + im * c);
  }
}

// ---------------- rope on q_bf[row][h*192+128..192] -> qcat[h][row][512..576] ----------------
__global__ __launch_bounds__(256) void rope_pack_q(const u16* __restrict__ q, const float* __restrict__ freq,
                                                   u16* __restrict__ qcat) {
  const int row = blockIdx.x;
  const int l = row & 1023;
  const int h = threadIdx.x >> 4, t = threadIdx.x & 15;
  const u16* qs = q + (size_t)row * 3072 + h * 192 + 128;
  u16* qd = qcat + ((size_t)h * 4096 + row) * 576 + 512;
  const float* fr = freq + (size_t)l * 64;
#pragma unroll
  for (int i = 0; i < 2; ++i) {
    const int j = 2 * t + i;
    const float re = b2f(qs[2 * j]), im = b2f(qs[2 * j + 1]);
    const float c = fr[2 * j], s = fr[2 * j + 1];
    qd[2 * j] = f2b(re * c - im * s);
    qd[2 * j + 1] = f2b(re * s + im * c);
  }
}

// ---------------- bf16 NT GEMM (m97-style): 128x128 tile, BK=64, global_load_lds w16 ----------------
// Optional z-batch via element strides sA/sB/sC.
template <typename OUT>
__global__ __launch_bounds__(256) void gemm_nt_bf16(const u16* __restrict__ A, const u16* __restrict__ B,
                                                    OUT* __restrict__ C, int K, int lda, int ldb, int ldc,
                                                    long sA, long sB, long sC) {
  __shared__ u16 lA[128 * 64];
  __shared__ u16 lB[128 * 64];
  const int tid = threadIdx.x, lane = tid & 63, w = tid >> 6;
  const int m = lane & 15, g = lane >> 4;
  const int wm = (w & 1) * 64, wn = (w >> 1) * 64;
  const int m0 = blockIdx.y * 128, n0 = blockIdx.x * 128;
  A += (long)blockIdx.z * sA;
  B += (long)blockIdx.z * sB;
  C += (long)blockIdx.z * sC;
  const int lrow = lane >> 3, lcol = (lane & 7) * 8;
  f32x4 acc[4][4];
#pragma unroll
  for (int i = 0; i < 4; ++i)
#pragma unroll
    for (int j = 0; j < 4; ++j) acc[i][j] = (f32x4)(0.0f);

  for (int k0 = 0; k0 < K; k0 += 64) {
    __syncthreads();
#pragma unroll
    for (int c = 0; c < 4; ++c) {
      const int ch = w * 4 + c;
      glds16(A + (size_t)(m0 + ch * 8 + lrow) * lda + k0 + lcol, &lA[ch * 512]);
      glds16(B + (size_t)(n0 + ch * 8 + lrow) * ldb + k0 + lcol, &lB[ch * 512]);
    }
    __syncthreads();
#pragma unroll
    for (int ks = 0; ks < 2; ++ks) {
      bf16x8 af[4], bfr[4];
#pragma unroll
      for (int i = 0; i < 4; ++i) {
        af[i] = *(const bf16x8*)&lA[(wm + i * 16 + m) * 64 + ks * 32 + g * 8];
        bfr[i] = *(const bf16x8*)&lB[(wn + i * 16 + m) * 64 + ks * 32 + g * 8];
      }
#pragma unroll
      for (int i = 0; i < 4; ++i)
#pragma unroll
        for (int j = 0; j < 4; ++j) acc[i][j] = MFMA16(af[i], bfr[j], acc[i][j]);
    }
  }
  // C/D layout: col = lane&15, row = (lane>>4)*4 + reg
#pragma unroll
  for (int i = 0; i < 4; ++i)
#pragma unroll
    for (int j = 0; j < 4; ++j)
#pragma unroll
      for (int jj = 0; jj < 4; ++jj) {
        const size_t off = (size_t)(m0 + wm + i * 16 + g * 4 + jj) * ldc + n0 + wn + j * 16 + m;
        if constexpr (sizeof(OUT) == 2) C[off] = f2b(acc[i][j][jj]);
        else C[off] = acc[i][j][jj];
      }
}

// ---------------- fused MLA attention, 8 heads per block (KV staged once) ----------------
// grid 256 blocks (1/CU), 512 thr = 8 waves; wave w owns head hg*8+w.
// latent_out written in-place into qcat[h][row][0:512].
// VT and QL use XOR slot-swizzle (slot ^= (m>>1)&3) to kill 8-way bank conflicts.
__global__ __launch_bounds__(512, 2) void mla_attn(
    u16* __restrict__ qcat,         // (16, 4096, 576): in = [q_abs|q_rope], out[0:512] = latent
    const u16* __restrict__ kvc,    // (4096, 576)
    const u16* __restrict__ kvT) {  // (4, 512, 1024) latent transposed
  __shared__ u16 SM[35584];        // [0,19200): K tile (32 x stride 600); [19200,35584): V^T (512 x 32)
  __shared__ u16 QL[36864];        // wave-private Q frags ks=9..17 (slot-swizzled)
  u16* KL = SM;
  u16* VT = SM + 19200;
  const int tid = threadIdx.x, lane = tid & 63, w = tid >> 6;   // w = 0..7
  const int m = lane & 15, g = lane >> 4;
  // swizzle: f and f+8 share (qp, b) and land on the same XCD (id % 8)
  const int f = (int)blockIdx.x;
  const int group = (f & 7) * 16 + (f >> 4);   // 0..127
  const int hg = (f >> 3) & 1;
  const int qp = group & 31;
  const int b = group >> 5;
  const int h = hg * 8 + w;
  const float scale = 0.07216878364870323f; // 1/sqrt(192)
  const u16* kvb = kvc + (size_t)b * 1024 * 576;
  const u16* kvTb = kvT + (size_t)b * 512 * 1024;
  u16* qlw = &QL[w * 4608];                  // this wave's Q-LDS (9 x 512 u16)
  const int sg8 = (g ^ ((m >> 1) & 3)) * 8;  // bank-spread slot for VT/QL

#pragma unroll 1
  for (int ps = 0; ps < 2; ++ps) {
    const int qt = ps ? (63 - qp) : qp;
    const int l0 = qt * 16;
    const int row = l0 + m;                  // q position of lane's column
    const int nt = (qt >> 1) + 1;            // tiles with t0 <= l0+15

    // prologue: qh[0..8] persistent in regs; qh[9..17] -> wave-private LDS (swizzled slot)
    bf16x8 qh[9];
    {
      const u16* qb = qcat + ((size_t)h * 4096 + b * 1024 + row) * 576 + g * 8;
#pragma unroll
      for (int ks = 0; ks < 9; ++ks) qh[ks] = *(const bf16x8*)(qb + ks * 32);
#pragma unroll
      for (int kk = 0; kk < 9; ++kk) {
        bf16x8 v = *(const bf16x8*)(qb + (9 + kk) * 32);
        *(bf16x8*)&qlw[kk * 512 + m * 32 + sg8] = v;
      }
    }

    f32x4 o[32];
#pragma unroll
    for (int i = 0; i < 32; ++i) o[i] = (f32x4)(0.0f);
    float mrow = -INFINITY, ssum = 0.f;

#pragma unroll 1
    for (int it = 0; it < nt; ++it) {
      const int t0 = it * 32;
      __syncthreads();                       // all waves done reading prev KL/VT (and prev-ps Ob)
      // V^T tile via async global->LDS: pre-swizzled global source so that
      // within-chunk slot s holds tq = s ^ ((l>>3)&3)  (l>>3 == m>>1 of the reader)
#pragma unroll
      for (int c = 0; c < 4; ++c) {
        const int cc = w * 4 + c;
        glds16(kvTb + (size_t)(cc * 16 + (lane >> 2)) * 1024 + t0 +
                   (((lane & 3) ^ ((lane >> 3) & 3)) * 8),
               &VT[cc * 512]);
      }
      // K tile: direct reg staging (transient registers)
#pragma unroll
      for (int k = 0; k < 4; ++k) {
        const int s = tid + k * 512, t = s / 72, c8 = (s % 72) * 8;
        *(bf16x8*)&KL[t * 600 + c8] = *(const bf16x8*)(kvb + (size_t)(t0 + t) * 576 + c8);
      }
      if (tid < 256) {
        const int s = 2048 + tid, t = s / 72, c8 = (s % 72) * 8;
        *(bf16x8*)&KL[t * 600 + c8] = *(const bf16x8*)(kvb + (size_t)(t0 + t) * 576 + c8);
      }
      __syncthreads();                       // drains glds16 + ds_writes
      // QK^T (swapped): A = K rows, B = q-frags (regs for ks<9, LDS for ks>=9)
      f32x4 st0 = (f32x4)(0.0f), st1 = (f32x4)(0.0f);
      __builtin_amdgcn_s_setprio(1);
#pragma unroll
      for (int ks = 0; ks < 9; ++ks) {
        bf16x8 a0 = *(const bf16x8*)&KL[m * 600 + ks * 32 + g * 8];
        bf16x8 a1 = *(const bf16x8*)&KL[(m + 16) * 600 + ks * 32 + g * 8];
        st0 = MFMA16(a0, qh[ks], st0);
        st1 = MFMA16(a1, qh[ks], st1);
      }
#pragma unroll
      for (int ks = 9; ks < 18; ++ks) {
        bf16x8 a0 = *(const bf16x8*)&KL[m * 600 + ks * 32 + g * 8];
        bf16x8 a1 = *(const bf16x8*)&KL[(m + 16) * 600 + ks * 32 + g * 8];
        const bf16x8 bq = *(const bf16x8*)&qlw[(ks - 9) * 512 + m * 32 + sg8];
        st0 = MFMA16(a0, bq, st0);
        st1 = MFMA16(a1, bq, st1);
      }
      __builtin_amdgcn_s_setprio(0);
      float p[8];
      float mt = -INFINITY;
#pragma unroll
      for (int j = 0; j < 4; ++j) {
        const int ta = t0 + 4 * g + j;
        const float sa = (ta <= row) ? st0[j] * scale : -INFINITY;
        const float sb = (ta + 16 <= row) ? st1[j] * scale : -INFINITY;
        p[j] = sa; p[4 + j] = sb;
        mt = fmaxf(mt, fmaxf(sa, sb));
      }
      mt = fmaxf(mt, __shfl_xor(mt, 16, 64));
      mt = fmaxf(mt, __shfl_xor(mt, 32, 64));
      // T13 defer-max: only rescale when the row max actually grows
      if (__any(mt > mrow + 8.0f)) {
        const float mnew = fmaxf(mrow, mt);
        const float corr = __expf(mrow - mnew);
        float cj[4];
#pragma unroll
        for (int j = 0; j < 4; ++j) cj[j] = __shfl(corr, 4 * g + j, 64);
#pragma unroll
        for (int i = 0; i < 32; ++i) {
          o[i][0] *= cj[0]; o[i][1] *= cj[1]; o[i][2] *= cj[2]; o[i][3] *= cj[3];
        }
        ssum *= corr;
        mrow = mnew;
      }
      float psum = 0.f;
#pragma unroll
      for (int i = 0; i < 8; ++i) { p[i] = __expf(p[i] - mrow); psum += p[i]; }
      psum += __shfl_xor(psum, 16, 64);
      psum += __shfl_xor(psum, 32, 64);
      ssum += psum;
      const bf16x8 pa = quad_gather(g, m, pk2(p[0], p[1]), pk2(p[2], p[3]),
                                          pk2(p[4], p[5]), pk2(p[6], p[7]));
      __builtin_amdgcn_s_setprio(1);
#pragma unroll
      for (int nf = 0; nf < 32; ++nf) {
        const bf16x8 bfr = *(const bf16x8*)&VT[(nf * 16 + m) * 32 + sg8];
        o[nf] = MFMA16(pa, bfr, o[nf]);
      }
      __builtin_amdgcn_s_setprio(0);
    }

    // normalize
    {
      const float inv = 1.f / ssum;
      float ij[4];
#pragma unroll
      for (int j = 0; j < 4; ++j) ij[j] = __shfl(inv, 4 * g + j, 64);
#pragma unroll
      for (int i = 0; i < 32; ++i) {
        o[i][0] *= ij[0]; o[i][1] *= ij[1]; o[i][2] *= ij[2]; o[i][3] *= ij[3];
      }
    }
    __syncthreads();   // all waves done with KL/VT; reuse SM as per-wave O staging
    // write latent_out in-place into qcat[h][b*1024+l0 .. +15][0:512]
    u16* Ob = &SM[w * 4224];                 // per-wave 16 x 264
#pragma unroll
    for (int hh = 0; hh < 2; ++hh) {
#pragma unroll
      for (int i = 0; i < 16; ++i)
#pragma unroll
        for (int j = 0; j < 4; ++j)
          Ob[(4 * g + j) * 264 + i * 16 + m] = f2b(o[hh * 16 + i][j]);
      u16* lat = qcat + ((size_t)h * 4096 + b * 1024 + l0) * 576 + hh * 256;
#pragma unroll
      for (int k = 0; k < 8; ++k) {
        const int cc = lane + k * 64;        // 0..511: 16 rows x 32 chunks of 8
        const int r = cc >> 5, c8 = (cc & 31) * 8;
        *(bf16x8*)(lat + (size_t)r * 576 + c8) = *(const bf16x8*)&Ob[r * 264 + c8];
      }
    }
  }
}

extern "C" void kernel_launch(void* const* d_in, const int* in_sizes, int n_in,
                              void* d_out, int out_size, void* d_ws, size_t ws_size,
                              hipStream_t stream) {
  const float* x        = (const float*)d_in[0];
  const float* freq     = (const float*)d_in[2];
  const float* Wq_down  = (const float*)d_in[4];
  const float* Wq_up    = (const float*)d_in[5];
  const float* Wkv_down = (const float*)d_in[6];
  const float* Wkv_up   = (const float*)d_in[7];
  const float* Wout     = (const float*)d_in[8];
  const float* rms_q_w  = (const float*)d_in[9];
  const float* rms_kv_w = (const float*)d_in[10];
  float* out = (float*)d_out;

  // Phase-overlapped arena, total 115.9 MB (< proven 120.6 MB budget).
  char* B = (char*)d_ws;                           // 75,497,472 B
  char* A = B + (size_t)75497472;                  // 25,165,824 B
  char* C = A + (size_t)25165824;                  // 15,204,352 B
  // B region, phases 1-3 (all dead before qcat is written):
  u16*   x_bf = (u16*)(B);                         // 16,777,216
  float* t0   = (float*)(B + 16777216);            // 16,777,216
  u16*   t0b  = (u16*)(B + 33554432);              //  8,388,608
  u16*   wqd  = (u16*)(B + 41943040);              //  4,194,304
  u16*   wqu  = (u16*)(B + 46137344);              //  6,291,456
  u16*   wkvd = (u16*)(B + 52428800);              //  2,621,440
  float* kvp  = (float*)(B + 55050240);            // 10,485,760 (ends 65,536,000)
  // B region, phase 4-6: qcat (becomes latent in-place)
  u16*   qcat  = (u16*)(B);                        // 75,497,472
  // A region: q_bf (phases 2-4), then vout + woutb (phase 6-7)
  u16*   q_bf = (u16*)(A);                         // 25,165,824
  u16*   vout = (u16*)(A);                         // 16,777,216
  u16*   woutb = (u16*)(A + 16777216);             //  8,388,608 (after q_bf dead)
  // C region: persistent small buffers
  u16*   kvc  = (u16*)(C);                         //  4,718,592
  u16*   kvT  = (u16*)(C + 4718592);               //  4,194,304
  u16*   wupt = (u16*)(C + 8912896);               //  2,097,152
  u16*   wkvu = (u16*)(C + 11010048);              //  4,194,304

  // conversions (merged) + weight transpose
  conv_all<<<8320, 256, 0, stream>>>(x, Wq_down, Wq_up, Wkv_up, Wkv_down,
                                     x_bf, wqd, wqu, wkvu, wkvd);
  transpose_wup<<<dim3(16, 4, 16), 256, 0, stream>>>(Wkv_up, wupt);
  // q path
  gemm_nt_bf16<float><<<dim3(8, 32), 256, 0, stream>>>(x_bf, wqd, t0, 2048, 2048, 2048, 1024, 0, 0, 0);
  rmsnorm1024_b<<<4096, 64, 0, stream>>>(t0, rms_q_w, t0b);
  gemm_nt_bf16<u16><<<dim3(24, 32), 256, 0, stream>>>(t0b, wqu, q_bf, 1024, 1024, 1024, 3072, 0, 0, 0);
  // kv path
  gemm_nt_bf16<float><<<dim3(5, 32), 256, 0, stream>>>(x_bf, wkvd, kvp, 2048, 2048, 2048, 640, 0, 0, 0);
  prep_kv<<<4096, 64, 0, stream>>>(kvp, freq, rms_kv_w, kvc);
  transpose_kvT<<<dim3(32, 16, 4), 256, 0, stream>>>(kvc, kvT);
  // qcat = [q_abs | rope(q_rope)]  (overwrites B phase-1 buffers; they are dead)
  rope_pack_q<<<4096, 256, 0, stream>>>(q_bf, freq, qcat);
  gemm_nt_bf16<u16><<<dim3(4, 32, 16), 256, 0, stream>>>(q_bf, wupt, qcat, 128, 3072, 128, 576,
                                                         192, (long)512 * 128, (long)4096 * 576);
  // fused attention: qcat[...][0:512] becomes latent_out in-place (q_bf dead)
  mla_attn<<<dim3(256), 512, 0, stream>>>(qcat, kvc, kvT);
  // v_out = latent @ Wv^T per head (batched): vout[row][h*128+d]
  gemm_nt_bf16<u16><<<dim3(1, 32, 16), 256, 0, stream>>>(
      qcat, wkvu + (size_t)128 * 512, vout, 512, 576, 512, 2048,
      (long)4096 * 576, (long)256 * 512, 128);
  // final projection (woutb into dead upper-A region)
  conv_f2b<<<2048, 256, 0, stream>>>(Wout, woutb);
  gemm_nt_bf16<float><<<dim3(16, 32), 256, 0, stream>>>(vout, woutb, out, 2048, 2048, 2048, 2048, 0, 0, 0);
}

// Round 14
// 350.835 us; speedup vs baseline: 2.1524x; 1.1469x over previous
//
#include <hip/hip_runtime.h>
#include <stdint.h>

typedef float f32x4 __attribute__((ext_vector_type(4)));
typedef short bf16x8 __attribute__((ext_vector_type(8)));
typedef int i32x4 __attribute__((ext_vector_type(4)));
typedef unsigned short u16;
typedef unsigned int u32;

#define MFMA16(a, b, c) __builtin_amdgcn_mfma_f32_16x16x32_bf16(a, b, c, 0, 0, 0)

__device__ __forceinline__ u16 f2b(float f) {
  union { float f; u32 u; } a; a.f = f;
  u32 r = a.u + 0x7FFF + ((a.u >> 16) & 1);
  return (u16)(r >> 16);
}
__device__ __forceinline__ float b2f(u16 b) {
  union { u32 u; float f; } a; a.u = ((u32)b) << 16;
  return a.f;
}
__device__ __forceinline__ u32 pk2(float x, float y) {
  return (u32)f2b(x) | ((u32)f2b(y) << 16);
}
__device__ __forceinline__ void glds16(const void* g, void* l) {
  __builtin_amdgcn_global_load_lds(
      (const __attribute__((address_space(1))) unsigned int*)g,
      (__attribute__((address_space(3))) unsigned int*)l, 16, 0, 0);
}

// quad-gather: lanes (m, g) hold lo (4 vals at idx 4g+j) and hi (idx 16+4g+j),
// packed as 2 dwords each. Returns 8 vals at idx 8g..8g+7 for this lane.
__device__ __forceinline__ bf16x8 quad_gather(int g, int m, u32 lo0, u32 lo1, u32 hi0, u32 hi1) {
  const int srcA = m + 16 * ((2 * g) & 3);
  const int srcB = m + 16 * ((2 * g + 1) & 3);
  const u32 Al0 = __shfl((int)lo0, srcA, 64), Al1 = __shfl((int)lo1, srcA, 64);
  const u32 Ah0 = __shfl((int)hi0, srcA, 64), Ah1 = __shfl((int)hi1, srcA, 64);
  const u32 Bl0 = __shfl((int)lo0, srcB, 64), Bl1 = __shfl((int)lo1, srcB, 64);
  const u32 Bh0 = __shfl((int)hi0, srcB, 64), Bh1 = __shfl((int)hi1, srcB, 64);
  i32x4 r;
  r.x = (int)((g < 2) ? Al0 : Ah0);
  r.y = (int)((g < 2) ? Al1 : Ah1);
  r.z = (int)((g < 2) ? Bl0 : Bh0);
  r.w = (int)((g < 2) ? Bl1 : Bh1);
  return __builtin_bit_cast(bf16x8, r);
}

__device__ __forceinline__ void conv8(const float* __restrict__ s, u16* __restrict__ d, size_t idx) {
  const float4* s4 = (const float4*)s;
  float4 a = s4[idx * 2], b = s4[idx * 2 + 1];
  i32x4 o;
  o.x = (int)pk2(a.x, a.y); o.y = (int)pk2(a.z, a.w);
  o.z = (int)pk2(b.x, b.y); o.w = (int)pk2(b.z, b.w);
  *(i32x4*)(d + idx * 8) = o;
}

// ---------------- bf16 NT GEMM core (m97-style): 128x128 tile, BK=64, glds16 w16 ----------------
template <typename OUT>
__device__ __forceinline__ void gemm_core(const u16* __restrict__ A, const u16* __restrict__ B,
                                          OUT* __restrict__ C, int K, int lda, int ldb, int ldc,
                                          int m0, int n0, u16* lA, u16* lB) {
  const int tid = threadIdx.x, lane = tid & 63, w = tid >> 6;
  const int m = lane & 15, g = lane >> 4;
  const int wm = (w & 1) * 64, wn = (w >> 1) * 64;
  const int lrow = lane >> 3, lcol = (lane & 7) * 8;
  f32x4 acc[4][4];
#pragma unroll
  for (int i = 0; i < 4; ++i)
#pragma unroll
    for (int j = 0; j < 4; ++j) acc[i][j] = (f32x4)(0.0f);

  for (int k0 = 0; k0 < K; k0 += 64) {
    __syncthreads();
#pragma unroll
    for (int c = 0; c < 4; ++c) {
      const int ch = w * 4 + c;
      glds16(A + (size_t)(m0 + ch * 8 + lrow) * lda + k0 + lcol, &lA[ch * 512]);
      glds16(B + (size_t)(n0 + ch * 8 + lrow) * ldb + k0 + lcol, &lB[ch * 512]);
    }
    __syncthreads();
#pragma unroll
    for (int ks = 0; ks < 2; ++ks) {
      bf16x8 af[4], bfr[4];
#pragma unroll
      for (int i = 0; i < 4; ++i) {
        af[i] = *(const bf16x8*)&lA[(wm + i * 16 + m) * 64 + ks * 32 + g * 8];
        bfr[i] = *(const bf16x8*)&lB[(wn + i * 16 + m) * 64 + ks * 32 + g * 8];
      }
#pragma unroll
      for (int i = 0; i < 4; ++i)
#pragma unroll
        for (int j = 0; j < 4; ++j) acc[i][j] = MFMA16(af[i], bfr[j], acc[i][j]);
    }
  }
  // C/D layout: col = lane&15, row = (lane>>4)*4 + reg
#pragma unroll
  for (int i = 0; i < 4; ++i)
#pragma unroll
    for (int j = 0; j < 4; ++j)
#pragma unroll
      for (int jj = 0; jj < 4; ++jj) {
        const size_t off = (size_t)(m0 + wm + i * 16 + g * 4 + jj) * ldc + n0 + wn + j * 16 + m;
        if constexpr (sizeof(OUT) == 2) C[off] = f2b(acc[i][j][jj]);
        else C[off] = acc[i][j][jj];
      }
}

// ---------------- merged: conversions (x + 4 weights) and wupt transpose ----------------
__global__ __launch_bounds__(256) void conv_wup_all(
    const float* __restrict__ x, const float* __restrict__ wqd_s, const float* __restrict__ wqu_s,
    const float* __restrict__ wkvu_s, const float* __restrict__ wkvd_s,
    u16* __restrict__ x_d, u16* __restrict__ wqd_d, u16* __restrict__ wqu_d,
    u16* __restrict__ wkvu_d, u16* __restrict__ wkvd_d, u16* __restrict__ wupt) {
  __shared__ float tile[32][33];
  int bb = blockIdx.x;
  if (bb < 4096) { conv8(x, x_d, (size_t)bb * 256 + threadIdx.x); return; }
  bb -= 4096;
  if (bb < 1024) { conv8(wqd_s, wqd_d, (size_t)bb * 256 + threadIdx.x); return; }
  bb -= 1024;
  if (bb < 1536) { conv8(wqu_s, wqu_d, (size_t)bb * 256 + threadIdx.x); return; }
  bb -= 1536;
  if (bb < 1024) { conv8(wkvu_s, wkvu_d, (size_t)bb * 256 + threadIdx.x); return; }
  bb -= 1024;
  if (bb < 640) {  // Wkv_down (576,2048) -> (640,2048) zero-padded
    const size_t idx = (size_t)bb * 256 + threadIdx.x;
    const size_t e0 = idx * 8;
    const int row = (int)(e0 >> 11);
    i32x4 o;
    if (row < 576) {
      const float4* s4 = (const float4*)wkvd_s;
      float4 a = s4[idx * 2], b = s4[idx * 2 + 1];
      o.x = (int)pk2(a.x, a.y); o.y = (int)pk2(a.z, a.w);
      o.z = (int)pk2(b.x, b.y); o.w = (int)pk2(b.z, b.w);
    } else {
      o.x = 0; o.y = 0; o.z = 0; o.w = 0;
    }
    *(i32x4*)(wkvd_d + e0) = o;
    return;
  }
  bb -= 640;
  {  // transpose_wup: wupt[h][k][d] = Wkv_up[h*256+d][k]; bb in [0,1024)
    const int nt = bb & 15, dt = (bb >> 4) & 3, h = bb >> 6;
    const int tx = threadIdx.x & 31, ty = threadIdx.x >> 5;
#pragma unroll
    for (int i = 0; i < 4; ++i)
      tile[ty + i * 8][tx] = wkvu_s[(size_t)(h * 256 + dt * 32 + ty + i * 8) * 512 + nt * 32 + tx];
    __syncthreads();
#pragma unroll
    for (int i = 0; i < 4; ++i)
      wupt[(size_t)(h * 512 + nt * 32 + ty + i * 8) * 128 + dt * 32 + tx] = f2b(tile[tx][ty + i * 8]);
  }
}

// ---------------- merged: GEMM1 (x@Wqd -> t0) + GEMM3 (x@Wkvd -> kvp), grid (13,32) ----------------
__global__ __launch_bounds__(256) void gemm_qd_kvd(const u16* __restrict__ x_bf,
                                                   const u16* __restrict__ wqd,
                                                   const u16* __restrict__ wkvd,
                                                   float* __restrict__ t0, float* __restrict__ kvp) {
  __shared__ u16 lA[128 * 64];
  __shared__ u16 lB[128 * 64];
  const int bx = blockIdx.x, m0 = blockIdx.y * 128;
  const u16* B;
  float* C;
  int n0, ldc;
  if (bx < 8) { B = wqd; C = t0; n0 = bx * 128; ldc = 1024; }
  else        { B = wkvd; C = kvp; n0 = (bx - 8) * 128; ldc = 640; }
  gemm_core<float>(x_bf, B, C, 2048, 2048, 2048, ldc, m0, n0, lA, lB);
}

// ---------------- merged: rmsnorm(t0->t0b) + prep_kv(kvp->kvc), 8192 x 64 ----------------
__global__ __launch_bounds__(64) void norm_both(const float* __restrict__ t0, const float* __restrict__ rqw,
                                                u16* __restrict__ t0b, const float* __restrict__ kvp,
                                                const float* __restrict__ freq, const float* __restrict__ rkw,
                                                u16* __restrict__ kvc) {
  const int lane = threadIdx.x;
  if (blockIdx.x < 4096) {
    const int row = blockIdx.x;
    const float4* p = (const float4*)(t0 + (size_t)row * 1024);
    const float4* w4 = (const float4*)rqw;
    float4 v[4];
    float ss = 0.f;
#pragma unroll
    for (int i = 0; i < 4; ++i) {
      v[i] = p[lane * 4 + i];
      ss += v[i].x * v[i].x + v[i].y * v[i].y + v[i].z * v[i].z + v[i].w * v[i].w;
    }
#pragma unroll
    for (int off = 32; off >= 1; off >>= 1) ss += __shfl_xor(ss, off, 64);
    const float rms = rsqrtf(ss * (1.0f / 1024.0f) + 1e-6f);
    u16* ob = t0b + (size_t)row * 1024 + lane * 16;
#pragma unroll
    for (int i2 = 0; i2 < 2; ++i2) {
      float4 a = v[i2 * 2], wa = w4[lane * 4 + i2 * 2];
      float4 b = v[i2 * 2 + 1], wb = w4[lane * 4 + i2 * 2 + 1];
      i32x4 pk;
      pk.x = (int)pk2(a.x * rms * wa.x, a.y * rms * wa.y);
      pk.y = (int)pk2(a.z * rms * wa.z, a.w * rms * wa.w);
      pk.z = (int)pk2(b.x * rms * wb.x, b.y * rms * wb.y);
      pk.w = (int)pk2(b.z * rms * wb.z, b.w * rms * wb.w);
      *(i32x4*)(ob + i2 * 8) = pk;
    }
    return;
  }
  const int row = blockIdx.x - 4096;
  const int l = row & 1023;
  const float* src = kvp + (size_t)row * 640;
  const float4* s4 = (const float4*)src;
  const float4* w4 = (const float4*)rkw;
  float4 v[2];
  float ss = 0.f;
#pragma unroll
  for (int i = 0; i < 2; ++i) {
    v[i] = s4[lane * 2 + i];
    ss += v[i].x * v[i].x + v[i].y * v[i].y + v[i].z * v[i].z + v[i].w * v[i].w;
  }
#pragma unroll
  for (int off = 32; off >= 1; off >>= 1) ss += __shfl_xor(ss, off, 64);
  const float rms = rsqrtf(ss * (1.0f / 512.0f) + 1e-6f);
  u16* dst = kvc + (size_t)row * 576;
  {
    float4 a = v[0], wa = w4[lane * 2];
    float4 b = v[1], wb = w4[lane * 2 + 1];
    i32x4 pk;
    pk.x = (int)pk2(a.x * rms * wa.x, a.y * rms * wa.y);
    pk.y = (int)pk2(a.z * rms * wa.z, a.w * rms * wa.w);
    pk.z = (int)pk2(b.x * rms * wb.x, b.y * rms * wb.y);
    pk.w = (int)pk2(b.z * rms * wb.z, b.w * rms * wb.w);
    *(i32x4*)(dst + lane * 8) = pk;
  }
  if (lane < 32) {
    const int j = lane;
    const float re = src[512 + 2 * j], im = src[512 + 2 * j + 1];
    const float c = freq[(l * 32 + j) * 2], s = freq[(l * 32 + j) * 2 + 1];
    dst[512 + 2 * j] = f2b(re * c - im * s);
    dst[512 + 2 * j + 1] = f2b(re * s + im * c);
  }
}

// ---------------- merged: q GEMM (t0b@Wqu -> q_bf, 768 blk) + transpose_kvT (2048 blk) ----------------
__global__ __launch_bounds__(256) void gemm_q_kvT(const u16* __restrict__ t0b, const u16* __restrict__ wqu,
                                                  u16* __restrict__ q_bf, const u16* __restrict__ kvc,
                                                  u16* __restrict__ kvT) {
  __shared__ u16 lA[128 * 64];
  __shared__ u16 lB[128 * 64];
  const int id = blockIdx.x;
  if (id < 768) {
    const int bx = id % 24, by = id / 24;
    gemm_core<u16>(t0b, wqu, q_bf, 1024, 1024, 1024, 3072, by * 128, bx * 128, lA, lB);
    return;
  }
  {  // transpose_kvT: kvT[b][c][t] = kvc[b*1024+t][c]
    const int id2 = id - 768;
    const int tt = id2 & 31, ct = (id2 >> 5) & 15, b = id2 >> 9;
    u16(*tile)[33] = (u16(*)[33])lA;
    const int tx = threadIdx.x & 31, ty = threadIdx.x >> 5;
#pragma unroll
    for (int i = 0; i < 4; ++i)
      tile[ty + i * 8][tx] = kvc[(size_t)(b * 1024 + tt * 32 + ty + i * 8) * 576 + ct * 32 + tx];
    __syncthreads();
#pragma unroll
    for (int i = 0; i < 4; ++i)
      kvT[(size_t)(b * 512 + ct * 32 + ty + i * 8) * 1024 + tt * 32 + tx] = tile[tx][ty + i * 8];
  }
}

// ---------------- merged: q_abs batched GEMM (2048 blk) + rope_pack (4096 blk) ----------------
__global__ __launch_bounds__(256) void rope_qabs(const u16* __restrict__ q_bf, const u16* __restrict__ wupt,
                                                 const float* __restrict__ freq, u16* __restrict__ qcat) {
  __shared__ u16 lA[128 * 64];
  __shared__ u16 lB[128 * 64];
  const int id = blockIdx.x;
  if (id < 2048) {
    const int bx = id & 3, by = (id >> 2) & 31, bz = id >> 7;
    gemm_core<u16>(q_bf + bz * 192, wupt + (size_t)bz * 512 * 128, qcat + (size_t)bz * 4096 * 576,
                   128, 3072, 128, 576, by * 128, bx * 128, lA, lB);
    return;
  }
  {  // rope_pack: qcat[h][row][512..576]
    const int row = id - 2048;
    const int l = row & 1023;
    const int h = threadIdx.x >> 4, t = threadIdx.x & 15;
    const u16* qs = q_bf + (size_t)row * 3072 + h * 192 + 128;
    u16* qd = qcat + ((size_t)h * 4096 + row) * 576 + 512;
    const float* fr = freq + (size_t)l * 64;
#pragma unroll
    for (int i = 0; i < 2; ++i) {
      const int j = 2 * t + i;
      const float re = b2f(qs[2 * j]), im = b2f(qs[2 * j + 1]);
      const float c = fr[2 * j], s = fr[2 * j + 1];
      qd[2 * j] = f2b(re * c - im * s);
      qd[2 * j + 1] = f2b(re * s + im * c);
    }
  }
}

// ---------------- fused MLA attention (UNCHANGED from R11/R13 verified) ----------------
__global__ __launch_bounds__(512, 2) void mla_attn(
    u16* __restrict__ qcat,         // (16, 4096, 576): in = [q_abs|q_rope], out[0:512] = latent
    const u16* __restrict__ kvc,    // (4096, 576)
    const u16* __restrict__ kvT) {  // (4, 512, 1024) latent transposed
  __shared__ u16 SM[35584];        // [0,19200): K tile (32 x stride 600); [19200,35584): V^T (512 x 32)
  __shared__ u16 QL[36864];        // wave-private Q frags ks=9..17 (slot-swizzled)
  u16* KL = SM;
  u16* VT = SM + 19200;
  const int tid = threadIdx.x, lane = tid & 63, w = tid >> 6;   // w = 0..7
  const int m = lane & 15, g = lane >> 4;
  const int f = (int)blockIdx.x;
  const int group = (f & 7) * 16 + (f >> 4);   // 0..127
  const int hg = (f >> 3) & 1;
  const int qp = group & 31;
  const int b = group >> 5;
  const int h = hg * 8 + w;
  const float scale = 0.07216878364870323f; // 1/sqrt(192)
  const u16* kvb = kvc + (size_t)b * 1024 * 576;
  const u16* kvTb = kvT + (size_t)b * 512 * 1024;
  u16* qlw = &QL[w * 4608];                  // this wave's Q-LDS (9 x 512 u16)
  const int sg8 = (g ^ ((m >> 1) & 3)) * 8;  // bank-spread slot for VT/QL

#pragma unroll 1
  for (int ps = 0; ps < 2; ++ps) {
    const int qt = ps ? (63 - qp) : qp;
    const int l0 = qt * 16;
    const int row = l0 + m;                  // q position of lane's column
    const int nt = (qt >> 1) + 1;            // tiles with t0 <= l0+15

    // prologue: qh[0..8] persistent in regs; qh[9..17] -> wave-private LDS (swizzled slot)
    bf16x8 qh[9];
    {
      const u16* qb = qcat + ((size_t)h * 4096 + b * 1024 + row) * 576 + g * 8;
#pragma unroll
      for (int ks = 0; ks < 9; ++ks) qh[ks] = *(const bf16x8*)(qb + ks * 32);
#pragma unroll
      for (int kk = 0; kk < 9; ++kk) {
        bf16x8 v = *(const bf16x8*)(qb + (9 + kk) * 32);
        *(bf16x8*)&qlw[kk * 512 + m * 32 + sg8] = v;
      }
    }

    f32x4 o[32];
#pragma unroll
    for (int i = 0; i < 32; ++i) o[i] = (f32x4)(0.0f);
    float mrow = -INFINITY, ssum = 0.f;

#pragma unroll 1
    for (int it = 0; it < nt; ++it) {
      const int t0 = it * 32;
      __syncthreads();                       // all waves done reading prev KL/VT (and prev-ps Ob)
#pragma unroll
      for (int c = 0; c < 4; ++c) {
        const int cc = w * 4 + c;
        glds16(kvTb + (size_t)(cc * 16 + (lane >> 2)) * 1024 + t0 +
                   (((lane & 3) ^ ((lane >> 3) & 3)) * 8),
               &VT[cc * 512]);
      }
#pragma unroll
      for (int k = 0; k < 4; ++k) {
        const int s = tid + k * 512, t = s / 72, c8 = (s % 72) * 8;
        *(bf16x8*)&KL[t * 600 + c8] = *(const bf16x8*)(kvb + (size_t)(t0 + t) * 576 + c8);
      }
      if (tid < 256) {
        const int s = 2048 + tid, t = s / 72, c8 = (s % 72) * 8;
        *(bf16x8*)&KL[t * 600 + c8] = *(const bf16x8*)(kvb + (size_t)(t0 + t) * 576 + c8);
      }
      __syncthreads();                       // drains glds16 + ds_writes
      f32x4 st0 = (f32x4)(0.0f), st1 = (f32x4)(0.0f);
      __builtin_amdgcn_s_setprio(1);
#pragma unroll
      for (int ks = 0; ks < 9; ++ks) {
        bf16x8 a0 = *(const bf16x8*)&KL[m * 600 + ks * 32 + g * 8];
        bf16x8 a1 = *(const bf16x8*)&KL[(m + 16) * 600 + ks * 32 + g * 8];
        st0 = MFMA16(a0, qh[ks], st0);
        st1 = MFMA16(a1, qh[ks], st1);
      }
#pragma unroll
      for (int ks = 9; ks < 18; ++ks) {
        bf16x8 a0 = *(const bf16x8*)&KL[m * 600 + ks * 32 + g * 8];
        bf16x8 a1 = *(const bf16x8*)&KL[(m + 16) * 600 + ks * 32 + g * 8];
        const bf16x8 bq = *(const bf16x8*)&qlw[(ks - 9) * 512 + m * 32 + sg8];
        st0 = MFMA16(a0, bq, st0);
        st1 = MFMA16(a1, bq, st1);
      }
      __builtin_amdgcn_s_setprio(0);
      float p[8];
      float mt = -INFINITY;
#pragma unroll
      for (int j = 0; j < 4; ++j) {
        const int ta = t0 + 4 * g + j;
        const float sa = (ta <= row) ? st0[j] * scale : -INFINITY;
        const float sb = (ta + 16 <= row) ? st1[j] * scale : -INFINITY;
        p[j] = sa; p[4 + j] = sb;
        mt = fmaxf(mt, fmaxf(sa, sb));
      }
      mt = fmaxf(mt, __shfl_xor(mt, 16, 64));
      mt = fmaxf(mt, __shfl_xor(mt, 32, 64));
      if (__any(mt > mrow + 8.0f)) {
        const float mnew = fmaxf(mrow, mt);
        const float corr = __expf(mrow - mnew);
        float cj[4];
#pragma unroll
        for (int j = 0; j < 4; ++j) cj[j] = __shfl(corr, 4 * g + j, 64);
#pragma unroll
        for (int i = 0; i < 32; ++i) {
          o[i][0] *= cj[0]; o[i][1] *= cj[1]; o[i][2] *= cj[2]; o[i][3] *= cj[3];
        }
        ssum *= corr;
        mrow = mnew;
      }
      float psum = 0.f;
#pragma unroll
      for (int i = 0; i < 8; ++i) { p[i] = __expf(p[i] - mrow); psum += p[i]; }
      psum += __shfl_xor(psum, 16, 64);
      psum += __shfl_xor(psum, 32, 64);
      ssum += psum;
      const bf16x8 pa = quad_gather(g, m, pk2(p[0], p[1]), pk2(p[2], p[3]),
                                          pk2(p[4], p[5]), pk2(p[6], p[7]));
      __builtin_amdgcn_s_setprio(1);
#pragma unroll
      for (int nf = 0; nf < 32; ++nf) {
        const bf16x8 bfr = *(const bf16x8*)&VT[(nf * 16 + m) * 32 + sg8];
        o[nf] = MFMA16(pa, bfr, o[nf]);
      }
      __builtin_amdgcn_s_setprio(0);
    }

    {
      const float inv = 1.f / ssum;
      float ij[4];
#pragma unroll
      for (int j = 0; j < 4; ++j) ij[j] = __shfl(inv, 4 * g + j, 64);
#pragma unroll
      for (int i = 0; i < 32; ++i) {
        o[i][0] *= ij[0]; o[i][1] *= ij[1]; o[i][2] *= ij[2]; o[i][3] *= ij[3];
      }
    }
    __syncthreads();   // all waves done with KL/VT; reuse SM as per-wave O staging
    u16* Ob = &SM[w * 4224];                 // per-wave 16 x 264
#pragma unroll
    for (int hh = 0; hh < 2; ++hh) {
#pragma unroll
      for (int i = 0; i < 16; ++i)
#pragma unroll
        for (int j = 0; j < 4; ++j)
          Ob[(4 * g + j) * 264 + i * 16 + m] = f2b(o[hh * 16 + i][j]);
      u16* lat = qcat + ((size_t)h * 4096 + b * 1024 + l0) * 576 + hh * 256;
#pragma unroll
      for (int k = 0; k < 8; ++k) {
        const int cc = lane + k * 64;        // 0..511: 16 rows x 32 chunks of 8
        const int r = cc >> 5, c8 = (cc & 31) * 8;
        *(bf16x8*)(lat + (size_t)r * 576 + c8) = *(const bf16x8*)&Ob[r * 264 + c8];
      }
    }
  }
}

// ---------------- merged: vout batched GEMM (512 blk) + Wout conv (2048 blk) ----------------
__global__ __launch_bounds__(256) void gemm_vout_conv(const u16* __restrict__ qcat,
                                                      const u16* __restrict__ wkvu,
                                                      u16* __restrict__ vout,
                                                      const float* __restrict__ Wout,
                                                      u16* __restrict__ woutb) {
  __shared__ u16 lA[128 * 64];
  __shared__ u16 lB[128 * 64];
  const int id = blockIdx.x;
  if (id < 512) {
    const int by = id & 31, bz = id >> 5;
    gemm_core<u16>(qcat + (size_t)bz * 4096 * 576, wkvu + (size_t)128 * 512 + (size_t)bz * 256 * 512,
                   vout + (size_t)bz * 128, 512, 576, 512, 2048, by * 128, 0, lA, lB);
    return;
  }
  conv8(Wout, woutb, (size_t)(id - 512) * 256 + threadIdx.x);
}

// ---------------- final projection GEMM ----------------
__global__ __launch_bounds__(256) void gemm_final(const u16* __restrict__ vout, const u16* __restrict__ woutb,
                                                  float* __restrict__ out) {
  __shared__ u16 lA[128 * 64];
  __shared__ u16 lB[128 * 64];
  gemm_core<float>(vout, woutb, out, 2048, 2048, 2048, 2048, blockIdx.y * 128, blockIdx.x * 128, lA, lB);
}

extern "C" void kernel_launch(void* const* d_in, const int* in_sizes, int n_in,
                              void* d_out, int out_size, void* d_ws, size_t ws_size,
                              hipStream_t stream) {
  const float* x        = (const float*)d_in[0];
  const float* freq     = (const float*)d_in[2];
  const float* Wq_down  = (const float*)d_in[4];
  const float* Wq_up    = (const float*)d_in[5];
  const float* Wkv_down = (const float*)d_in[6];
  const float* Wkv_up   = (const float*)d_in[7];
  const float* Wout     = (const float*)d_in[8];
  const float* rms_q_w  = (const float*)d_in[9];
  const float* rms_kv_w = (const float*)d_in[10];
  float* out = (float*)d_out;

  // Phase-overlapped arena, total 115.9 MB (< proven 120.6 MB budget).
  char* B = (char*)d_ws;                           // 75,497,472 B
  char* A = B + (size_t)75497472;                  // 25,165,824 B
  char* C = A + (size_t)25165824;                  // 15,204,352 B
  u16*   x_bf = (u16*)(B);                         // 16,777,216
  float* t0   = (float*)(B + 16777216);            // 16,777,216
  u16*   t0b  = (u16*)(B + 33554432);              //  8,388,608
  u16*   wqd  = (u16*)(B + 41943040);              //  4,194,304
  u16*   wqu  = (u16*)(B + 46137344);              //  6,291,456
  u16*   wkvd = (u16*)(B + 52428800);              //  2,621,440
  float* kvp  = (float*)(B + 55050240);            // 10,485,760 (ends 65,536,000)
  u16*   qcat  = (u16*)(B);                        // 75,497,472 (phase 4-6)
  u16*   q_bf = (u16*)(A);                         // 25,165,824 (phase 2-4)
  u16*   vout = (u16*)(A);                         // 16,777,216 (phase 6-7)
  u16*   woutb = (u16*)(A + 16777216);             //  8,388,608 (after q_bf dead)
  u16*   kvc  = (u16*)(C);                         //  4,718,592
  u16*   kvT  = (u16*)(C + 4718592);               //  4,194,304
  u16*   wupt = (u16*)(C + 8912896);               //  2,097,152
  u16*   wkvu = (u16*)(C + 11010048);              //  4,194,304

  // 1. conversions + wupt transpose (all read only original inputs)
  conv_wup_all<<<9344, 256, 0, stream>>>(x, Wq_down, Wq_up, Wkv_up, Wkv_down,
                                         x_bf, wqd, wqu, wkvu, wkvd, wupt);
  // 2. x@Wqd -> t0  |  x@Wkvd -> kvp
  gemm_qd_kvd<<<dim3(13, 32), 256, 0, stream>>>(x_bf, wqd, wkvd, t0, kvp);
  // 3. rmsnorm(t0)->t0b  |  prep_kv(kvp)->kvc
  norm_both<<<8192, 64, 0, stream>>>(t0, rms_q_w, t0b, kvp, freq, rms_kv_w, kvc);
  // 4. t0b@Wqu -> q_bf  |  transpose kvc -> kvT
  gemm_q_kvT<<<2816, 256, 0, stream>>>(t0b, wqu, q_bf, kvc, kvT);
  // 5. q_abs GEMM -> qcat[0:512]  |  rope -> qcat[512:576]   (overwrites B phase-1; dead)
  rope_qabs<<<6144, 256, 0, stream>>>(q_bf, wupt, freq, qcat);
  // 6. fused attention: qcat[...][0:512] becomes latent_out in-place (q_bf dead)
  mla_attn<<<dim3(256), 512, 0, stream>>>(qcat, kvc, kvT);
  // 7. latent@Wv -> vout  |  conv Wout -> woutb
  gemm_vout_conv<<<2560, 256, 0, stream>>>(qcat, wkvu, vout, Wout, woutb);
  // 8. vout@Wout^T -> out
  gemm_final<<<dim3(16, 32), 256, 0, stream>>>(vout, woutb, out);
}

// Round 16
// 350.769 us; speedup vs baseline: 2.1528x; 1.0002x over previous
//
#include <hip/hip_runtime.h>
#include <stdint.h>

typedef float f32x4 __attribute__((ext_vector_type(4)));
typedef short bf16x8 __attribute__((ext_vector_type(8)));
typedef int i32x4 __attribute__((ext_vector_type(4)));
typedef unsigned short u16;
typedef unsigned int u32;

#define MFMA16(a, b, c) __builtin_amdgcn_mfma_f32_16x16x32_bf16(a, b, c, 0, 0, 0)

__device__ __forceinline__ u16 f2b(float f) {
  union { float f; u32 u; } a; a.f = f;
  u32 r = a.u + 0x7FFF + ((a.u >> 16) & 1);
  return (u16)(r >> 16);
}
__device__ __forceinline__ float b2f(u16 b) {
  union { u32 u; float f; } a; a.u = ((u32)b) << 16;
  return a.f;
}
__device__ __forceinline__ u32 pk2(float x, float y) {
  return (u32)f2b(x) | ((u32)f2b(y) << 16);
}
__device__ __forceinline__ void glds16(const void* g, void* l) {
  __builtin_amdgcn_global_load_lds(
      (const __attribute__((address_space(1))) unsigned int*)g,
      (__attribute__((address_space(3))) unsigned int*)l, 16, 0, 0);
}

// quad-gather: lanes (m, g) hold lo (4 vals at idx 4g+j) and hi (idx 16+4g+j),
// packed as 2 dwords each. Returns 8 vals at idx 8g..8g+7 for this lane.
__device__ __forceinline__ bf16x8 quad_gather(int g, int m, u32 lo0, u32 lo1, u32 hi0, u32 hi1) {
  const int srcA = m + 16 * ((2 * g) & 3);
  const int srcB = m + 16 * ((2 * g + 1) & 3);
  const u32 Al0 = __shfl((int)lo0, srcA, 64), Al1 = __shfl((int)lo1, srcA, 64);
  const u32 Ah0 = __shfl((int)hi0, srcA, 64), Ah1 = __shfl((int)hi1, srcA, 64);
  const u32 Bl0 = __shfl((int)lo0, srcB, 64), Bl1 = __shfl((int)lo1, srcB, 64);
  const u32 Bh0 = __shfl((int)hi0, srcB, 64), Bh1 = __shfl((int)hi1, srcB, 64);
  i32x4 r;
  r.x = (int)((g < 2) ? Al0 : Ah0);
  r.y = (int)((g < 2) ? Al1 : Ah1);
  r.z = (int)((g < 2) ? Bl0 : Bh0);
  r.w = (int)((g < 2) ? Bl1 : Bh1);
  return __builtin_bit_cast(bf16x8, r);
}

__device__ __forceinline__ void conv8(const float* __restrict__ s, u16* __restrict__ d, size_t idx) {
  const float4* s4 = (const float4*)s;
  float4 a = s4[idx * 2], b = s4[idx * 2 + 1];
  i32x4 o;
  o.x = (int)pk2(a.x, a.y); o.y = (int)pk2(a.z, a.w);
  o.z = (int)pk2(b.x, b.y); o.w = (int)pk2(b.z, b.w);
  *(i32x4*)(d + idx * 8) = o;
}

// ---------------- bf16 NT GEMM core (m97-style): 128x128 tile, BK=64, glds16 w16 ----------------
template <typename OUT>
__device__ __forceinline__ void gemm_core(const u16* __restrict__ A, const u16* __restrict__ B,
                                          OUT* __restrict__ C, int K, int lda, int ldb, int ldc,
                                          int m0, int n0, u16* lA, u16* lB) {
  const int tid = threadIdx.x, lane = tid & 63, w = tid >> 6;
  const int m = lane & 15, g = lane >> 4;
  const int wm = (w & 1) * 64, wn = (w >> 1) * 64;
  const int lrow = lane >> 3, lcol = (lane & 7) * 8;
  f32x4 acc[4][4];
#pragma unroll
  for (int i = 0; i < 4; ++i)
#pragma unroll
    for (int j = 0; j < 4; ++j) acc[i][j] = (f32x4)(0.0f);

  for (int k0 = 0; k0 < K; k0 += 64) {
    __syncthreads();
#pragma unroll
    for (int c = 0; c < 4; ++c) {
      const int ch = w * 4 + c;
      glds16(A + (size_t)(m0 + ch * 8 + lrow) * lda + k0 + lcol, &lA[ch * 512]);
      glds16(B + (size_t)(n0 + ch * 8 + lrow) * ldb + k0 + lcol, &lB[ch * 512]);
    }
    __syncthreads();
#pragma unroll
    for (int ks = 0; ks < 2; ++ks) {
      bf16x8 af[4], bfr[4];
#pragma unroll
      for (int i = 0; i < 4; ++i) {
        af[i] = *(const bf16x8*)&lA[(wm + i * 16 + m) * 64 + ks * 32 + g * 8];
        bfr[i] = *(const bf16x8*)&lB[(wn + i * 16 + m) * 64 + ks * 32 + g * 8];
      }
#pragma unroll
      for (int i = 0; i < 4; ++i)
#pragma unroll
        for (int j = 0; j < 4; ++j) acc[i][j] = MFMA16(af[i], bfr[j], acc[i][j]);
    }
  }
  // C/D layout: col = lane&15, row = (lane>>4)*4 + reg
#pragma unroll
  for (int i = 0; i < 4; ++i)
#pragma unroll
    for (int j = 0; j < 4; ++j)
#pragma unroll
      for (int jj = 0; jj < 4; ++jj) {
        const size_t off = (size_t)(m0 + wm + i * 16 + g * 4 + jj) * ldc + n0 + wn + j * 16 + m;
        if constexpr (sizeof(OUT) == 2) C[off] = f2b(acc[i][j][jj]);
        else C[off] = acc[i][j][jj];
      }
}

// ---------------- merged: conversions (x + 4 weights) and wupt transpose ----------------
__global__ __launch_bounds__(256) void conv_wup_all(
    const float* __restrict__ x, const float* __restrict__ wqd_s, const float* __restrict__ wqu_s,
    const float* __restrict__ wkvu_s, const float* __restrict__ wkvd_s,
    u16* __restrict__ x_d, u16* __restrict__ wqd_d, u16* __restrict__ wqu_d,
    u16* __restrict__ wkvu_d, u16* __restrict__ wkvd_d, u16* __restrict__ wupt) {
  __shared__ float tile[32][33];
  int bb = blockIdx.x;
  if (bb < 4096) { conv8(x, x_d, (size_t)bb * 256 + threadIdx.x); return; }
  bb -= 4096;
  if (bb < 1024) { conv8(wqd_s, wqd_d, (size_t)bb * 256 + threadIdx.x); return; }
  bb -= 1024;
  if (bb < 1536) { conv8(wqu_s, wqu_d, (size_t)bb * 256 + threadIdx.x); return; }
  bb -= 1536;
  if (bb < 1024) { conv8(wkvu_s, wkvu_d, (size_t)bb * 256 + threadIdx.x); return; }
  bb -= 1024;
  if (bb < 640) {  // Wkv_down (576,2048) -> (640,2048) zero-padded
    const size_t idx = (size_t)bb * 256 + threadIdx.x;
    const size_t e0 = idx * 8;
    const int row = (int)(e0 >> 11);
    i32x4 o;
    if (row < 576) {
      const float4* s4 = (const float4*)wkvd_s;
      float4 a = s4[idx * 2], b = s4[idx * 2 + 1];
      o.x = (int)pk2(a.x, a.y); o.y = (int)pk2(a.z, a.w);
      o.z = (int)pk2(b.x, b.y); o.w = (int)pk2(b.z, b.w);
    } else {
      o.x = 0; o.y = 0; o.z = 0; o.w = 0;
    }
    *(i32x4*)(wkvd_d + e0) = o;
    return;
  }
  bb -= 640;
  {  // transpose_wup: wupt[h][k][d] = Wkv_up[h*256+d][k]; bb in [0,1024)
    const int nt = bb & 15, dt = (bb >> 4) & 3, h = bb >> 6;
    const int tx = threadIdx.x & 31, ty = threadIdx.x >> 5;
#pragma unroll
    for (int i = 0; i < 4; ++i)
      tile[ty + i * 8][tx] = wkvu_s[(size_t)(h * 256 + dt * 32 + ty + i * 8) * 512 + nt * 32 + tx];
    __syncthreads();
#pragma unroll
    for (int i = 0; i < 4; ++i)
      wupt[(size_t)(h * 512 + nt * 32 + ty + i * 8) * 128 + dt * 32 + tx] = f2b(tile[tx][ty + i * 8]);
  }
}

// ---------------- merged: GEMM1 (x@Wqd -> t0) + GEMM3 (x@Wkvd -> kvp), grid (13,32) ----------------
__global__ __launch_bounds__(256) void gemm_qd_kvd(const u16* __restrict__ x_bf,
                                                   const u16* __restrict__ wqd,
                                                   const u16* __restrict__ wkvd,
                                                   float* __restrict__ t0, float* __restrict__ kvp) {
  __shared__ u16 lA[128 * 64];
  __shared__ u16 lB[128 * 64];
  const int bx = blockIdx.x, m0 = blockIdx.y * 128;
  const u16* B;
  float* C;
  int n0, ldc;
  if (bx < 8) { B = wqd; C = t0; n0 = bx * 128; ldc = 1024; }
  else        { B = wkvd; C = kvp; n0 = (bx - 8) * 128; ldc = 640; }
  gemm_core<float>(x_bf, B, C, 2048, 2048, 2048, ldc, m0, n0, lA, lB);
}

// ---------------- merged: rmsnorm(t0->t0b) + prep_kv(kvp->kvc), 8192 x 64 ----------------
__global__ __launch_bounds__(64) void norm_both(const float* __restrict__ t0, const float* __restrict__ rqw,
                                                u16* __restrict__ t0b, const float* __restrict__ kvp,
                                                const float* __restrict__ freq, const float* __restrict__ rkw,
                                                u16* __restrict__ kvc) {
  const int lane = threadIdx.x;
  if (blockIdx.x < 4096) {
    const int row = blockIdx.x;
    const float4* p = (const float4*)(t0 + (size_t)row * 1024);
    const float4* w4 = (const float4*)rqw;
    float4 v[4];
    float ss = 0.f;
#pragma unroll
    for (int i = 0; i < 4; ++i) {
      v[i] = p[lane * 4 + i];
      ss += v[i].x * v[i].x + v[i].y * v[i].y + v[i].z * v[i].z + v[i].w * v[i].w;
    }
#pragma unroll
    for (int off = 32; off >= 1; off >>= 1) ss += __shfl_xor(ss, off, 64);
    const float rms = rsqrtf(ss * (1.0f / 1024.0f) + 1e-6f);
    u16* ob = t0b + (size_t)row * 1024 + lane * 16;
#pragma unroll
    for (int i2 = 0; i2 < 2; ++i2) {
      float4 a = v[i2 * 2], wa = w4[lane * 4 + i2 * 2];
      float4 b = v[i2 * 2 + 1], wb = w4[lane * 4 + i2 * 2 + 1];
      i32x4 pk;
      pk.x = (int)pk2(a.x * rms * wa.x, a.y * rms * wa.y);
      pk.y = (int)pk2(a.z * rms * wa.z, a.w * rms * wa.w);
      pk.z = (int)pk2(b.x * rms * wb.x, b.y * rms * wb.y);
      pk.w = (int)pk2(b.z * rms * wb.z, b.w * rms * wb.w);
      *(i32x4*)(ob + i2 * 8) = pk;
    }
    return;
  }
  const int row = blockIdx.x - 4096;
  const int l = row & 1023;
  const float* src = kvp + (size_t)row * 640;
  const float4* s4 = (const float4*)src;
  const float4* w4 = (const float4*)rkw;
  float4 v[2];
  float ss = 0.f;
#pragma unroll
  for (int i = 0; i < 2; ++i) {
    v[i] = s4[lane * 2 + i];
    ss += v[i].x * v[i].x + v[i].y * v[i].y + v[i].z * v[i].z + v[i].w * v[i].w;
  }
#pragma unroll
  for (int off = 32; off >= 1; off >>= 1) ss += __shfl_xor(ss, off, 64);
  const float rms = rsqrtf(ss * (1.0f / 512.0f) + 1e-6f);
  u16* dst = kvc + (size_t)row * 576;
  {
    float4 a = v[0], wa = w4[lane * 2];
    float4 b = v[1], wb = w4[lane * 2 + 1];
    i32x4 pk;
    pk.x = (int)pk2(a.x * rms * wa.x, a.y * rms * wa.y);
    pk.y = (int)pk2(a.z * rms * wa.z, a.w * rms * wa.w);
    pk.z = (int)pk2(b.x * rms * wb.x, b.y * rms * wb.y);
    pk.w = (int)pk2(b.z * rms * wb.z, b.w * rms * wb.w);
    *(i32x4*)(dst + lane * 8) = pk;
  }
  if (lane < 32) {
    const int j = lane;
    const float re = src[512 + 2 * j], im = src[512 + 2 * j + 1];
    const float c = freq[(l * 32 + j) * 2], s = freq[(l * 32 + j) * 2 + 1];
    dst[512 + 2 * j] = f2b(re * c - im * s);
    dst[512 + 2 * j + 1] = f2b(re * s + im * c);
  }
}

// ---------------- merged: q GEMM (t0b@Wqu -> q_bf, 768 blk) + transpose_kvT (2048 blk) ----------------
__global__ __launch_bounds__(256) void gemm_q_kvT(const u16* __restrict__ t0b, const u16* __restrict__ wqu,
                                                  u16* __restrict__ q_bf, const u16* __restrict__ kvc,
                                                  u16* __restrict__ kvT) {
  __shared__ u16 lA[128 * 64];
  __shared__ u16 lB[128 * 64];
  const int id = blockIdx.x;
  if (id < 768) {
    const int bx = id % 24, by = id / 24;
    gemm_core<u16>(t0b, wqu, q_bf, 1024, 1024, 1024, 3072, by * 128, bx * 128, lA, lB);
    return;
  }
  {  // transpose_kvT: kvT[b][c][t] = kvc[b*1024+t][c]
    const int id2 = id - 768;
    const int tt = id2 & 31, ct = (id2 >> 5) & 15, b = id2 >> 9;
    u16(*tile)[33] = (u16(*)[33])lA;
    const int tx = threadIdx.x & 31, ty = threadIdx.x >> 5;
#pragma unroll
    for (int i = 0; i < 4; ++i)
      tile[ty + i * 8][tx] = kvc[(size_t)(b * 1024 + tt * 32 + ty + i * 8) * 576 + ct * 32 + tx];
    __syncthreads();
#pragma unroll
    for (int i = 0; i < 4; ++i)
      kvT[(size_t)(b * 512 + ct * 32 + ty + i * 8) * 1024 + tt * 32 + tx] = tile[tx][ty + i * 8];
  }
}

// ---------------- merged: q_abs batched GEMM (2048 blk) + rope_pack (4096 blk) ----------------
__global__ __launch_bounds__(256) void rope_qabs(const u16* __restrict__ q_bf, const u16* __restrict__ wupt,
                                                 const float* __restrict__ freq, u16* __restrict__ qcat) {
  __shared__ u16 lA[128 * 64];
  __shared__ u16 lB[128 * 64];
  const int id = blockIdx.x;
  if (id < 2048) {
    const int bx = id & 3, by = (id >> 2) & 31, bz = id >> 7;
    gemm_core<u16>(q_bf + bz * 192, wupt + (size_t)bz * 512 * 128, qcat + (size_t)bz * 4096 * 576,
                   128, 3072, 128, 576, by * 128, bx * 128, lA, lB);
    return;
  }
  {  // rope_pack: qcat[h][row][512..576]
    const int row = id - 2048;
    const int l = row & 1023;
    const int h = threadIdx.x >> 4, t = threadIdx.x & 15;
    const u16* qs = q_bf + (size_t)row * 3072 + h * 192 + 128;
    u16* qd = qcat + ((size_t)h * 4096 + row) * 576 + 512;
    const float* fr = freq + (size_t)l * 64;
#pragma unroll
    for (int i = 0; i < 2; ++i) {
      const int j = 2 * t + i;
      const float re = b2f(qs[2 * j]), im = b2f(qs[2 * j + 1]);
      const float c = fr[2 * j], s = fr[2 * j + 1];
      qd[2 * j] = f2b(re * c - im * s);
      qd[2 * j + 1] = f2b(re * s + im * c);
    }
  }
}

// ---------------- fused MLA attention (R11-verified structure) ----------------
__global__ __launch_bounds__(512, 2) void mla_attn(
    u16* __restrict__ qcat,         // (16, 4096, 576): in = [q_abs|q_rope], out[0:512] = latent
    const u16* __restrict__ kvc,    // (4096, 576)
    const u16* __restrict__ kvT) {  // (4, 512, 1024) latent transposed
  __shared__ u16 SM[35584];        // [0,19200): K tile (32 x stride 600); [19200,35584): V^T (512 x 32)
  __shared__ u16 QL[36864];        // wave-private Q frags ks=9..17 (slot-swizzled)
  u16* KL = SM;
  u16* VT = SM + 19200;
  const int tid = threadIdx.x, lane = tid & 63, w = tid >> 6;   // w = 0..7
  const int m = lane & 15, g = lane >> 4;
  const int f = (int)blockIdx.x;
  const int group = (f & 7) * 16 + (f >> 4);   // 0..127
  const int hg = (f >> 3) & 1;
  const int qp = group & 31;
  const int b = group >> 5;
  const int h = hg * 8 + w;
  const float scale = 0.07216878364870323f; // 1/sqrt(192)
  const u16* kvb = kvc + (size_t)b * 1024 * 576;
  const u16* kvTb = kvT + (size_t)b * 512 * 1024;
  u16* qlw = &QL[w * 4608];                  // this wave's Q-LDS (9 x 512 u16)
  const int sg8 = (g ^ ((m >> 1) & 3)) * 8;  // bank-spread slot for VT/QL

#pragma unroll 1
  for (int ps = 0; ps < 2; ++ps) {
    const int qt = ps ? (63 - qp) : qp;
    const int l0 = qt * 16;
    const int row = l0 + m;                  // q position of lane's column
    const int nt = (qt >> 1) + 1;            // tiles with t0 <= l0+15

    // prologue: qh[0..8] persistent in regs; qh[9..17] -> wave-private LDS (swizzled slot)
    bf16x8 qh[9];
    {
      const u16* qb = qcat + ((size_t)h * 4096 + b * 1024 + row) * 576 + g * 8;
#pragma unroll
      for (int ks = 0; ks < 9; ++ks) qh[ks] = *(const bf16x8*)(qb + ks * 32);
#pragma unroll
      for (int kk = 0; kk < 9; ++kk) {
        bf16x8 v = *(const bf16x8*)(qb + (9 + kk) * 32);
        *(bf16x8*)&qlw[kk * 512 + m * 32 + sg8] = v;
      }
    }

    f32x4 o[32];
#pragma unroll
    for (int i = 0; i < 32; ++i) o[i] = (f32x4)(0.0f);
    float mrow = -INFINITY, ssum = 0.f;

#pragma unroll 1
    for (int it = 0; it < nt; ++it) {
      const int t0 = it * 32;
      __syncthreads();                       // all waves done reading prev KL/VT (and prev-ps Ob)
#pragma unroll
      for (int c = 0; c < 4; ++c) {
        const int cc = w * 4 + c;
        glds16(kvTb + (size_t)(cc * 16 + (lane >> 2)) * 1024 + t0 +
                   (((lane & 3) ^ ((lane >> 3) & 3)) * 8),
               &VT[cc * 512]);
      }
#pragma unroll
      for (int k = 0; k < 4; ++k) {
        const int s = tid + k * 512, t = s / 72, c8 = (s % 72) * 8;
        *(bf16x8*)&KL[t * 600 + c8] = *(const bf16x8*)(kvb + (size_t)(t0 + t) * 576 + c8);
      }
      if (tid < 256) {
        const int s = 2048 + tid, t = s / 72, c8 = (s % 72) * 8;
        *(bf16x8*)&KL[t * 600 + c8] = *(const bf16x8*)(kvb + (size_t)(t0 + t) * 576 + c8);
      }
      __syncthreads();                       // drains glds16 + ds_writes
      f32x4 st0 = (f32x4)(0.0f), st1 = (f32x4)(0.0f);
      __builtin_amdgcn_s_setprio(1);
#pragma unroll
      for (int ks = 0; ks < 9; ++ks) {
        bf16x8 a0 = *(const bf16x8*)&KL[m * 600 + ks * 32 + g * 8];
        bf16x8 a1 = *(const bf16x8*)&KL[(m + 16) * 600 + ks * 32 + g * 8];
        st0 = MFMA16(a0, qh[ks], st0);
        st1 = MFMA16(a1, qh[ks], st1);
      }
#pragma unroll
      for (int ks = 9; ks < 18; ++ks) {
        bf16x8 a0 = *(const bf16x8*)&KL[m * 600 + ks * 32 + g * 8];
        bf16x8 a1 = *(const bf16x8*)&KL[(m + 16) * 600 + ks * 32 + g * 8];
        const bf16x8 bq = *(const bf16x8*)&qlw[(ks - 9) * 512 + m * 32 + sg8];
        st0 = MFMA16(a0, bq, st0);
        st1 = MFMA16(a1, bq, st1);
      }
      __builtin_amdgcn_s_setprio(0);
      float p[8];
      float mt = -INFINITY;
#pragma unroll
      for (int j = 0; j < 4; ++j) {
        const int ta = t0 + 4 * g + j;
        const float sa = (ta <= row) ? st0[j] * scale : -INFINITY;
        const float sb = (ta + 16 <= row) ? st1[j] * scale : -INFINITY;
        p[j] = sa; p[4 + j] = sb;
        mt = fmaxf(mt, fmaxf(sa, sb));
      }
      mt = fmaxf(mt, __shfl_xor(mt, 16, 64));
      mt = fmaxf(mt, __shfl_xor(mt, 32, 64));
      if (__any(mt > mrow + 8.0f)) {
        const float mnew = fmaxf(mrow, mt);
        const float corr = __expf(mrow - mnew);
        float cj[4];
#pragma unroll
        for (int j = 0; j < 4; ++j) cj[j] = __shfl(corr, 4 * g + j, 64);
#pragma unroll
        for (int i = 0; i < 32; ++i) {
          o[i][0] *= cj[0]; o[i][1] *= cj[1]; o[i][2] *= cj[2]; o[i][3] *= cj[3];
        }
        ssum *= corr;
        mrow = mnew;
      }
      float psum = 0.f;
#pragma unroll
      for (int i = 0; i < 8; ++i) { p[i] = __expf(p[i] - mrow); psum += p[i]; }
      psum += __shfl_xor(psum, 16, 64);
      psum += __shfl_xor(psum, 32, 64);
      ssum += psum;
      const bf16x8 pa = quad_gather(g, m, pk2(p[0], p[1]), pk2(p[2], p[3]),
                                          pk2(p[4], p[5]), pk2(p[6], p[7]));
      __builtin_amdgcn_s_setprio(1);
#pragma unroll
      for (int nf = 0; nf < 32; ++nf) {
        const bf16x8 bfr = *(const bf16x8*)&VT[(nf * 16 + m) * 32 + sg8];
        o[nf] = MFMA16(pa, bfr, o[nf]);
      }
      __builtin_amdgcn_s_setprio(0);
    }

    {
      const float inv = 1.f / ssum;
      float ij[4];
#pragma unroll
      for (int j = 0; j < 4; ++j) ij[j] = __shfl(inv, 4 * g + j, 64);
#pragma unroll
      for (int i = 0; i < 32; ++i) {
        o[i][0] *= ij[0]; o[i][1] *= ij[1]; o[i][2] *= ij[2]; o[i][3] *= ij[3];
      }
    }
    __syncthreads();   // all waves done with KL/VT; reuse SM as per-wave O staging
    u16* Ob = &SM[w * 4224];                 // per-wave 16 x 264
#pragma unroll
    for (int hh = 0; hh < 2; ++hh) {
#pragma unroll
      for (int i = 0; i < 16; ++i)
#pragma unroll
        for (int j = 0; j < 4; ++j)
          Ob[(4 * g + j) * 264 + i * 16 + m] = f2b(o[hh * 16 + i][j]);
      u16* lat = qcat + ((size_t)h * 4096 + b * 1024 + l0) * 576 + hh * 256;
#pragma unroll
      for (int k = 0; k < 8; ++k) {
        const int cc = lane + k * 64;        // 0..511: 16 rows x 32 chunks of 8
        const int r = cc >> 5, c8 = (cc & 31) * 8;
        *(bf16x8*)(lat + (size_t)r * 576 + c8) = *(const bf16x8*)&Ob[r * 264 + c8];
      }
    }
  }
}

// ---------------- merged: vout batched GEMM (512 blk) + Wout conv (2048 blk) ----------------
__global__ __launch_bounds__(256) void gemm_vout_conv(const u16* __restrict__ qcat,
                                                      const u16* __restrict__ wkvu,
                                                      u16* __restrict__ vout,
                                                      const float* __restrict__ Wout,
                                                      u16* __restrict__ woutb) {
  __shared__ u16 lA[128 * 64];
  __shared__ u16 lB[128 * 64];
  const int id = blockIdx.x;
  if (id < 512) {
    const int by = id & 31, bz = id >> 5;
    gemm_core<u16>(qcat + (size_t)bz * 4096 * 576, wkvu + (size_t)128 * 512 + (size_t)bz * 256 * 512,
                   vout + (size_t)bz * 128, 512, 576, 512, 2048, by * 128, 0, lA, lB);
    return;
  }
  conv8(Wout, woutb, (size_t)(id - 512) * 256 + threadIdx.x);
}

// ---------------- final projection GEMM ----------------
__global__ __launch_bounds__(256) void gemm_final(const u16* __restrict__ vout, const u16* __restrict__ woutb,
                                                  float* __restrict__ out) {
  __shared__ u16 lA[128 * 64];
  __shared__ u16 lB[128 * 64];
  gemm_core<float>(vout, woutb, out, 2048, 2048, 2048, 2048, blockIdx.y * 128, blockIdx.x * 128, lA, lB);
}

extern "C" void kernel_launch(void* const* d_in, const int* in_sizes, int n_in,
                              void* d_out, int out_size, void* d_ws, size_t ws_size,
                              hipStream_t stream) {
  const float* x        = (const float*)d_in[0];
  const float* freq     = (const float*)d_in[2];
  const float* Wq_down  = (const float*)d_in[4];
  const float* Wq_up    = (const float*)d_in[5];
  const float* Wkv_down = (const float*)d_in[6];
  const float* Wkv_up   = (const float*)d_in[7];
  const float* Wout     = (const float*)d_in[8];
  const float* rms_q_w  = (const float*)d_in[9];
  const float* rms_kv_w = (const float*)d_in[10];
  float* out = (float*)d_out;

  // Phase-overlapped arena, total 115.9 MB (< proven 120.6 MB budget).
  char* B = (char*)d_ws;                           // 75,497,472 B
  char* A = B + (size_t)75497472;                  // 25,165,824 B
  char* C = A + (size_t)25165824;                  // 15,204,352 B
  u16*   x_bf = (u16*)(B);                         // 16,777,216
  float* t0   = (float*)(B + 16777216);            // 16,777,216
  u16*   t0b  = (u16*)(B + 33554432);              //  8,388,608
  u16*   wqd  = (u16*)(B + 41943040);              //  4,194,304
  u16*   wqu  = (u16*)(B + 46137344);              //  6,291,456
  u16*   wkvd = (u16*)(B + 52428800);              //  2,621,440
  float* kvp  = (float*)(B + 55050240);            // 10,485,760 (ends 65,536,000)
  u16*   qcat  = (u16*)(B);                        // 75,497,472 (phase 4-6)
  u16*   q_bf = (u16*)(A);                         // 25,165,824 (phase 2-4)
  u16*   vout = (u16*)(A);                         // 16,777,216 (phase 6-7)
  u16*   woutb = (u16*)(A + 16777216);             //  8,388,608 (after q_bf dead)
  u16*   kvc  = (u16*)(C);                         //  4,718,592
  u16*   kvT  = (u16*)(C + 4718592);               //  4,194,304
  u16*   wupt = (u16*)(C + 8912896);               //  2,097,152
  u16*   wkvu = (u16*)(C + 11010048);              //  4,194,304

  // 1. conversions + wupt transpose (all read only original inputs)
  conv_wup_all<<<9344, 256, 0, stream>>>(x, Wq_down, Wq_up, Wkv_up, Wkv_down,
                                         x_bf, wqd, wqu, wkvu, wkvd, wupt);
  // 2. x@Wqd -> t0  |  x@Wkvd -> kvp
  gemm_qd_kvd<<<dim3(13, 32), 256, 0, stream>>>(x_bf, wqd, wkvd, t0, kvp);
  // 3. rmsnorm(t0)->t0b  |  prep_kv(kvp)->kvc
  norm_both<<<8192, 64, 0, stream>>>(t0, rms_q_w, t0b, kvp, freq, rms_kv_w, kvc);
  // 4. t0b@Wqu -> q_bf  |  transpose kvc -> kvT
  gemm_q_kvT<<<2816, 256, 0, stream>>>(t0b, wqu, q_bf, kvc, kvT);
  // 5. q_abs GEMM -> qcat[0:512]  |  rope -> qcat[512:576]
  rope_qabs<<<6144, 256, 0, stream>>>(q_bf, wupt, freq, qcat);
  // 6. fused attention: qcat[...][0:512] becomes latent_out in-place (q_bf dead)
  mla_attn<<<dim3(256), 512, 0, stream>>>(qcat, kvc, kvT);
  // 7. latent@Wv -> vout  |  conv Wout -> woutb
  gemm_vout_conv<<<2560, 256, 0, stream>>>(qcat, wkvu, vout, Wout, woutb);
  // 8. vout@Wout^T -> out
  gemm_final<<<dim3(16, 32), 256, 0, stream>>>(vout, woutb, out);
}